// Round 4
// baseline (745.208 us; speedup 1.0000x reference)
//
#include <hip/hip_runtime.h>
#include <hip/hip_bf16.h>
#include <cstdint>
#include <cstddef>

typedef __attribute__((ext_vector_type(8))) short s16x8;
typedef __attribute__((ext_vector_type(4))) float f32x4;
typedef __attribute__((ext_vector_type(8))) float f32x8;
typedef __attribute__((ext_vector_type(8))) _Float16 h8;
typedef __attribute__((ext_vector_type(4))) _Float16 h4;

#define TT 2048
#define BB 4
#define EE 1024
#define HH 16
#define DD 64
#define MR 8192   // T*B rows

#define MFMA_BF16(a,b,c) __builtin_amdgcn_mfma_f32_16x16x32_bf16(a,b,c,0,0,0)
#define MFMA_F16(a,b,c)  __builtin_amdgcn_mfma_f32_16x16x32_f16(a,b,c,0,0,0)

__device__ __forceinline__ ushort f2bf(float f) {
  uint32_t u = __float_as_uint(f);
  u += 0x7fffu + ((u >> 16) & 1u);   // RNE
  return (ushort)(u >> 16);
}

// global -> LDS async copy, 16B per lane. LDS dest must be wave-uniform base + lane*16.
#define GL2L(g, l) __builtin_amdgcn_global_load_lds( \
    (__attribute__((address_space(1))) void*)(g), \
    (__attribute__((address_space(3))) void*)(l), 16, 0, 0)

// ---------------------------------------------------------------- cast fp32->bf16
__global__ void cast_f32_bf16(const float* __restrict__ in, ushort* __restrict__ out, int n4) {
  int stride = gridDim.x * blockDim.x;
  for (int i = blockIdx.x * blockDim.x + threadIdx.x; i < n4; i += stride) {
    float4 v = ((const float4*)in)[i];
    ushort4 o;
    o.x = f2bf(v.x); o.y = f2bf(v.y); o.z = f2bf(v.z); o.w = f2bf(v.w);
    ((ushort4*)out)[i] = o;
  }
}

// ---------------------------------------------------------------- QKV projection
// C[m][n] = sum_k A[m][k]*W[n][k] + bias[n];  m=(t*4+b), n = sec*1024 + h*64 + d
// Q scaled by 0.125 -> bf16 [b][h][t][d]; K -> bf16 same; V -> f16 transposed [b][h][d][t].
__global__ __launch_bounds__(256) void gemm_qkv(
    const ushort* __restrict__ A, const ushort* __restrict__ W,
    const float* __restrict__ bias,
    ushort* __restrict__ Qb, ushort* __restrict__ Kb, ushort* __restrict__ Vt)
{
  __shared__ ushort As[128 * 32];
  __shared__ ushort Bs[128 * 32];
  const int K = EE;
  int tid = threadIdx.x;
  int bn = blockIdx.x, bm = blockIdx.y;
  int brow = bm * 128, bcol = bn * 128;
  int lane = tid & 63, wid = tid >> 6;
  int wm = wid >> 1, wn = wid & 1;
  int lr = lane & 15, kg = lane >> 4;

  f32x4 zero = {0.f, 0.f, 0.f, 0.f};
  f32x4 acc[4][4];
#pragma unroll
  for (int i = 0; i < 4; i++)
#pragma unroll
    for (int j = 0; j < 4; j++) acc[i][j] = zero;

  int r0 = tid >> 2, c0 = (tid & 3) * 8;
  const ushort* Abase = A + (size_t)brow * K;
  const ushort* Wbase = W + (size_t)bcol * K;

  for (int k0 = 0; k0 < K; k0 += 32) {
    __syncthreads();
    GL2L(Abase + (size_t)r0 * K + k0 + c0,        &As[tid * 8]);
    GL2L(Abase + (size_t)(r0 + 64) * K + k0 + c0, &As[(tid + 256) * 8]);
    GL2L(Wbase + (size_t)r0 * K + k0 + c0,        &Bs[tid * 8]);
    GL2L(Wbase + (size_t)(r0 + 64) * K + k0 + c0, &Bs[(tid + 256) * 8]);
    __syncthreads();
    s16x8 af[4], bfr[4];
#pragma unroll
    for (int i = 0; i < 4; i++) af[i]  = *(const s16x8*)&As[(wm * 64 + i * 16 + lr) * 32 + kg * 8];
#pragma unroll
    for (int j = 0; j < 4; j++) bfr[j] = *(const s16x8*)&Bs[(wn * 64 + j * 16 + lr) * 32 + kg * 8];
#pragma unroll
    for (int i = 0; i < 4; i++)
#pragma unroll
      for (int j = 0; j < 4; j++)
        acc[i][j] = MFMA_BF16(af[i], bfr[j], acc[i][j]);
  }

#pragma unroll
  for (int i = 0; i < 4; i++)
#pragma unroll
    for (int j = 0; j < 4; j++) {
      int n = bcol + wn * 64 + j * 16 + lr;
      float bv = bias[n];
      int sec = n >> 10;
      int hd = n & 1023;
      int h = hd >> 6, d = hd & 63;
#pragma unroll
      for (int e = 0; e < 4; e++) {
        int m = brow + wm * 64 + i * 16 + kg * 4 + e;
        int t = m >> 2, b = m & 3;
        float v = acc[i][j][e] + bv;
        size_t hoff = (size_t)(b * HH + h);
        if (sec == 0)      Qb[(hoff * TT + t) * DD + d] = f2bf(v * 0.125f);
        else if (sec == 1) Kb[(hoff * TT + t) * DD + d] = f2bf(v);
        else { _Float16 hv = (_Float16)v; Vt[(hoff * DD + d) * TT + t] = *(ushort*)&hv; }
      }
    }
}

// ---------------------------------------------------------------- fused attention
// block = (qt, b): 16 q-rows x all 2048 keys x all 16 heads. 512 thr, 2 blocks/CU.
// Per head: QK^T (swapped mfma -> packed LDS writes, XOR swizzle), softmax
// (unnormalized exp kept in LDS f16) with avg accumulated in 64 regs/thread,
// PV f16 MFMA with (d-tile, k-half) waves + LDS partial reduction.
__global__ __launch_bounds__(512, 4) void attn_fused(
    const ushort* __restrict__ Qb, const ushort* __restrict__ Kb,
    const _Float16* __restrict__ Vt, ushort* __restrict__ attn,
    float* __restrict__ avgp)
{
  __shared__ _Float16 sc[16 * 2048];   // 64 KB, column-swizzled: col ^ ((row&7)<<3)
  __shared__ float scr[1024];          // 4 KB PV partial-reduction scratch
  __shared__ float invl[16];

  const int qt = blockIdx.x;      // 0..127
  const int b  = blockIdx.y;      // 0..3
  const int tid = threadIdx.x;
  const int lane = tid & 63;
  const int w = tid >> 6;         // wave 0..7
  const int m = lane & 15;
  const int kq = lane >> 4;       // frag k-chunk == C-layout row group
  const int t0 = qt * 16;

  // per-thread avg accumulator: rows w*2+u (u=0..1), cols (c*64+lane)*8+j
  f32x8 av[2][4];
#pragma unroll
  for (int u = 0; u < 2; u++)
#pragma unroll
    for (int c = 0; c < 4; c++) av[u][c] = (f32x8)(0.f);

  for (int h = 0; h < HH; ++h) {
    const size_t bh = (size_t)b * HH + h;

    // ---- Q fragments (bf16), Q pre-scaled by 1/8
    const ushort* qp = Qb + (bh * TT + t0) * DD;
    s16x8 q0 = *(const s16x8*)&qp[(size_t)m * DD + kq * 8];
    s16x8 q1 = *(const s16x8*)&qp[(size_t)m * DD + 32 + kq * 8];

    // ---- QK^T: wave w owns k-tiles w*16 .. w*16+15 (keys w*256..+255)
    const ushort* kbase = Kb + bh * TT * DD;
#pragma unroll 4
    for (int i = 0; i < 16; ++i) {
      int nt = w * 16 + i;
      const ushort* kr = kbase + (size_t)(nt * 16 + m) * DD + kq * 8;
      s16x8 a0 = *(const s16x8*)kr;
      s16x8 a1 = *(const s16x8*)(kr + 32);
      f32x4 c0 = {0.f, 0.f, 0.f, 0.f};
      c0 = MFMA_BF16(a0, q0, c0);
      c0 = MFMA_BF16(a1, q1, c0);
      // lane holds S[k = nt*16 + kq*4 + e][q = m] -> 4 k-consecutive f16, packed write
      int ksw = (nt * 16 + kq * 4) ^ ((m & 7) << 3);
      h4 p0;
#pragma unroll
      for (int e = 0; e < 4; e++) p0[e] = (_Float16)c0[e];
      *(h4*)&sc[(size_t)m * 2048 + ksw] = p0;
    }
    __syncthreads();

    // ---- softmax: wave w owns rows w*2, w*2+1; store UNNORMALIZED exp back;
    //      fold normalized-weight sum into av[] registers.
#pragma unroll
    for (int u = 0; u < 2; ++u) {
      int r = w * 2 + u;
      _Float16* rp = &sc[(size_t)r * 2048];
      int xr = (r & 7) << 3;
      float mx = -3e38f;
      h8 v[4];
#pragma unroll
      for (int c = 0; c < 4; ++c) {
        v[c] = *(const h8*)&rp[((c * 64 + lane) * 8) ^ xr];
#pragma unroll
        for (int j = 0; j < 8; j++) mx = fmaxf(mx, (float)v[c][j]);
      }
#pragma unroll
      for (int o = 32; o; o >>= 1) mx = fmaxf(mx, __shfl_xor(mx, o));
      float l = 0.f;
      h8 ev[4];
#pragma unroll
      for (int c = 0; c < 4; ++c) {
#pragma unroll
        for (int j = 0; j < 8; j++) { float e = __expf((float)v[c][j] - mx); l += e; ev[c][j] = (_Float16)e; }
        *(h8*)&rp[((c * 64 + lane) * 8) ^ xr] = ev[c];
      }
#pragma unroll
      for (int o = 32; o; o >>= 1) l += __shfl_xor(l, o);
      float inv = 1.0f / l;
      if (lane == 0) invl[r] = inv;
#pragma unroll
      for (int c = 0; c < 4; ++c)
#pragma unroll
        for (int j = 0; j < 8; j++)
          av[u][c][j] += (float)ev[c][j] * inv;
    }
    __syncthreads();

    // ---- PV: wave = (d-tile, k-half); V (f16) read once per block-head
    {
      int dtl = w & 3, kh = w >> 2;
      const _Float16* vb = Vt + bh * DD * TT + (size_t)(dtl * 16 + m) * TT + kh * 1024 + kq * 8;
      const _Float16* ap = &sc[(size_t)m * 2048];
      int xr = (m & 7) << 3;
      f32x4 acc0 = {0.f, 0.f, 0.f, 0.f};
#pragma unroll 4
      for (int s = 0; s < 32; ++s) {
        int ksw = (kh * 1024 + s * 32 + kq * 8) ^ xr;
        h8 bv = *(const h8*)(vb + s * 32);
        h8 a0 = *(const h8*)&ap[ksw];
        acc0 = MFMA_F16(a0, bv, acc0);
      }
      if (kh == 1) {
#pragma unroll
        for (int e = 0; e < 4; e++)
          scr[dtl * 256 + (kq * 4 + e) * 16 + m] = acc0[e];
      }
      __syncthreads();
      if (kh == 0) {
#pragma unroll
        for (int e = 0; e < 4; e++) {
          int ql = kq * 4 + e;
          float v0 = (acc0[e] + scr[dtl * 256 + ql * 16 + m]) * invl[ql];
          attn[((size_t)(t0 + ql) * BB + b) * EE + h * DD + dtl * 16 + m] = f2bf(v0);
        }
      }
    }
    __syncthreads();   // sc/scr reads done before next head overwrites
  }

  // ---- write avg once: row t0 + w*2+u, cols (c*64+lane)*8 .. +7
#pragma unroll
  for (int u = 0; u < 2; ++u) {
    float* gp = avgp + ((size_t)b * TT + t0 + w * 2 + u) * TT;
#pragma unroll
    for (int c = 0; c < 4; ++c) {
      int cb = (c * 64 + lane) * 8;
      float4 o0 = {av[u][c][0] * 0.0625f, av[u][c][1] * 0.0625f,
                   av[u][c][2] * 0.0625f, av[u][c][3] * 0.0625f};
      float4 o1 = {av[u][c][4] * 0.0625f, av[u][c][5] * 0.0625f,
                   av[u][c][6] * 0.0625f, av[u][c][7] * 0.0625f};
      ((float4*)(gp + cb))[0] = o0;
      ((float4*)(gp + cb))[1] = o1;
    }
  }
}

// ---------------------------------------------------------------- output projection
__global__ __launch_bounds__(256) void gemm_out(
    const ushort* __restrict__ A, const ushort* __restrict__ W,
    const float* __restrict__ bias, float* __restrict__ out)
{
  __shared__ ushort As[128 * 32];
  __shared__ ushort Bs[128 * 32];
  const int K = EE;
  int tid = threadIdx.x;
  int bn = blockIdx.x, bm = blockIdx.y;
  int brow = bm * 128, bcol = bn * 128;
  int lane = tid & 63, wid = tid >> 6;
  int wm = wid >> 1, wn = wid & 1;
  int lr = lane & 15, kg = lane >> 4;

  f32x4 zero = {0.f, 0.f, 0.f, 0.f};
  f32x4 acc[4][4];
#pragma unroll
  for (int i = 0; i < 4; i++)
#pragma unroll
    for (int j = 0; j < 4; j++) acc[i][j] = zero;

  int r0 = tid >> 2, c0 = (tid & 3) * 8;
  const ushort* Abase = A + (size_t)brow * K;
  const ushort* Wbase = W + (size_t)bcol * K;

  for (int k0 = 0; k0 < K; k0 += 32) {
    __syncthreads();
    GL2L(Abase + (size_t)r0 * K + k0 + c0,        &As[tid * 8]);
    GL2L(Abase + (size_t)(r0 + 64) * K + k0 + c0, &As[(tid + 256) * 8]);
    GL2L(Wbase + (size_t)r0 * K + k0 + c0,        &Bs[tid * 8]);
    GL2L(Wbase + (size_t)(r0 + 64) * K + k0 + c0, &Bs[(tid + 256) * 8]);
    __syncthreads();
    s16x8 af[4], bfr[4];
#pragma unroll
    for (int i = 0; i < 4; i++) af[i]  = *(const s16x8*)&As[(wm * 64 + i * 16 + lr) * 32 + kg * 8];
#pragma unroll
    for (int j = 0; j < 4; j++) bfr[j] = *(const s16x8*)&Bs[(wn * 64 + j * 16 + lr) * 32 + kg * 8];
#pragma unroll
    for (int i = 0; i < 4; i++)
#pragma unroll
      for (int j = 0; j < 4; j++)
        acc[i][j] = MFMA_BF16(af[i], bfr[j], acc[i][j]);
  }

#pragma unroll
  for (int i = 0; i < 4; i++)
#pragma unroll
    for (int j = 0; j < 4; j++) {
      int n = bcol + wn * 64 + j * 16 + lr;
      float bv = bias[n];
#pragma unroll
      for (int e = 0; e < 4; e++) {
        int m = brow + wm * 64 + i * 16 + kg * 4 + e;
        out[(size_t)m * EE + n] = acc[i][j][e] + bv;
      }
    }
}

// ---------------------------------------------------------------- launch
extern "C" void kernel_launch(void* const* d_in, const int* in_sizes, int n_in,
                              void* d_out, int out_size, void* d_ws, size_t ws_size,
                              hipStream_t stream) {
  const float* x  = (const float*)d_in[0];
  const float* w1 = (const float*)d_in[1];
  const float* b1 = (const float*)d_in[2];
  const float* w2 = (const float*)d_in[3];
  const float* b2 = (const float*)d_in[4];
  float* out = (float*)d_out;
  float* avg = out + (size_t)MR * EE;

  char* p = (char*)d_ws;
  ushort* Xb   = (ushort*)p; p += (size_t)MR * EE * 2;
  ushort* W1b  = (ushort*)p; p += (size_t)3 * EE * EE * 2;
  ushort* W2b  = (ushort*)p; p += (size_t)EE * EE * 2;
  ushort* Qb   = (ushort*)p; p += (size_t)BB * HH * TT * DD * 2;
  ushort* Kb   = (ushort*)p; p += (size_t)BB * HH * TT * DD * 2;
  ushort* Vt   = (ushort*)p; p += (size_t)BB * HH * TT * DD * 2;
  ushort* attn = (ushort*)p; p += (size_t)MR * EE * 2;
  (void)ws_size;

  cast_f32_bf16<<<1024, 256, 0, stream>>>(x,  Xb,  MR * EE / 4);
  cast_f32_bf16<<<512,  256, 0, stream>>>(w1, W1b, 3 * EE * EE / 4);
  cast_f32_bf16<<<256,  256, 0, stream>>>(w2, W2b, EE * EE / 4);
  gemm_qkv<<<dim3(24, 64), 256, 0, stream>>>(Xb, W1b, b1, Qb, Kb, Vt);
  attn_fused<<<dim3(TT / 16, BB), 512, 0, stream>>>(Qb, Kb, (const _Float16*)Vt, attn, avg);
  gemm_out<<<dim3(8, 64), 256, 0, stream>>>(attn, W2b, b2, out);
}

// Round 5
// 712.870 us; speedup vs baseline: 1.0454x; 1.0454x over previous
//
#include <hip/hip_runtime.h>
#include <hip/hip_bf16.h>
#include <cstdint>
#include <cstddef>

typedef __attribute__((ext_vector_type(8))) short s16x8;
typedef __attribute__((ext_vector_type(4))) float f32x4;
typedef __attribute__((ext_vector_type(8))) float f32x8;
typedef __attribute__((ext_vector_type(8))) _Float16 h8;
typedef __attribute__((ext_vector_type(4))) _Float16 h4;

#define TT 2048
#define BB 4
#define EE 1024
#define HH 16
#define DD 64
#define MR 8192   // T*B rows

#define MFMA_BF16(a,b,c) __builtin_amdgcn_mfma_f32_16x16x32_bf16(a,b,c,0,0,0)
#define MFMA_F16(a,b,c)  __builtin_amdgcn_mfma_f32_16x16x32_f16(a,b,c,0,0,0)

__device__ __forceinline__ ushort f2bf(float f) {
  uint32_t u = __float_as_uint(f);
  u += 0x7fffu + ((u >> 16) & 1u);   // RNE
  return (ushort)(u >> 16);
}

// global -> LDS async copy, 16B per lane. LDS dest must be wave-uniform base + lane*16.
#define GL2L(g, l) __builtin_amdgcn_global_load_lds( \
    (__attribute__((address_space(1))) void*)(g), \
    (__attribute__((address_space(3))) void*)(l), 16, 0, 0)

// ---------------------------------------------------------------- cast fp32->bf16
__global__ void cast_f32_bf16(const float* __restrict__ in, ushort* __restrict__ out, int n4) {
  int stride = gridDim.x * blockDim.x;
  for (int i = blockIdx.x * blockDim.x + threadIdx.x; i < n4; i += stride) {
    float4 v = ((const float4*)in)[i];
    ushort4 o;
    o.x = f2bf(v.x); o.y = f2bf(v.y); o.z = f2bf(v.z); o.w = f2bf(v.w);
    ((ushort4*)out)[i] = o;
  }
}

// ---------------------------------------------------------------- QKV projection
// C[m][n] = sum_k A[m][k]*W[n][k] + bias[n];  m=(t*4+b), n = sec*1024 + h*64 + d
// Q scaled by 0.125 -> bf16 [b][h][t][d]; K -> bf16 same; V -> f16 transposed [b][h][d][t].
__global__ __launch_bounds__(256) void gemm_qkv(
    const ushort* __restrict__ A, const ushort* __restrict__ W,
    const float* __restrict__ bias,
    ushort* __restrict__ Qb, ushort* __restrict__ Kb, ushort* __restrict__ Vt)
{
  __shared__ ushort As[128 * 32];
  __shared__ ushort Bs[128 * 32];
  const int K = EE;
  int tid = threadIdx.x;
  int bn = blockIdx.x, bm = blockIdx.y;
  int brow = bm * 128, bcol = bn * 128;
  int lane = tid & 63, wid = tid >> 6;
  int wm = wid >> 1, wn = wid & 1;
  int lr = lane & 15, kg = lane >> 4;

  f32x4 zero = {0.f, 0.f, 0.f, 0.f};
  f32x4 acc[4][4];
#pragma unroll
  for (int i = 0; i < 4; i++)
#pragma unroll
    for (int j = 0; j < 4; j++) acc[i][j] = zero;

  int r0 = tid >> 2, c0 = (tid & 3) * 8;
  const ushort* Abase = A + (size_t)brow * K;
  const ushort* Wbase = W + (size_t)bcol * K;

  for (int k0 = 0; k0 < K; k0 += 32) {
    __syncthreads();
    GL2L(Abase + (size_t)r0 * K + k0 + c0,        &As[tid * 8]);
    GL2L(Abase + (size_t)(r0 + 64) * K + k0 + c0, &As[(tid + 256) * 8]);
    GL2L(Wbase + (size_t)r0 * K + k0 + c0,        &Bs[tid * 8]);
    GL2L(Wbase + (size_t)(r0 + 64) * K + k0 + c0, &Bs[(tid + 256) * 8]);
    __syncthreads();
    s16x8 af[4], bfr[4];
#pragma unroll
    for (int i = 0; i < 4; i++) af[i]  = *(const s16x8*)&As[(wm * 64 + i * 16 + lr) * 32 + kg * 8];
#pragma unroll
    for (int j = 0; j < 4; j++) bfr[j] = *(const s16x8*)&Bs[(wn * 64 + j * 16 + lr) * 32 + kg * 8];
#pragma unroll
    for (int i = 0; i < 4; i++)
#pragma unroll
      for (int j = 0; j < 4; j++)
        acc[i][j] = MFMA_BF16(af[i], bfr[j], acc[i][j]);
  }

#pragma unroll
  for (int i = 0; i < 4; i++)
#pragma unroll
    for (int j = 0; j < 4; j++) {
      int n = bcol + wn * 64 + j * 16 + lr;
      float bv = bias[n];
      int sec = n >> 10;
      int hd = n & 1023;
      int h = hd >> 6, d = hd & 63;
#pragma unroll
      for (int e = 0; e < 4; e++) {
        int m = brow + wm * 64 + i * 16 + kg * 4 + e;
        int t = m >> 2, b = m & 3;
        float v = acc[i][j][e] + bv;
        size_t hoff = (size_t)(b * HH + h);
        if (sec == 0)      Qb[(hoff * TT + t) * DD + d] = f2bf(v * 0.125f);
        else if (sec == 1) Kb[(hoff * TT + t) * DD + d] = f2bf(v);
        else { _Float16 hv = (_Float16)v; Vt[(hoff * DD + d) * TT + t] = *(ushort*)&hv; }
      }
    }
}

// ---------------------------------------------------------------- fused attention
// block = (qt, b): 16 q-rows x all 2048 keys x all 16 heads. 512 thr, 2 blocks/CU.
// Per head: QK^T (swapped mfma -> packed LDS writes, XOR swizzle), softmax
// (unnormalized exp kept in LDS f16) with avg accumulated in 64 regs/thread,
// PV f16 MFMA with (d-tile, k-half) waves + LDS partial reduction.
// NOTE launch_bounds 2nd arg observed to behave as CUDA blocks/CU on this
// toolchain: cap = 512/(2N) VGPRs. N=2 -> 128-VGPR cap (4 waves/SIMD).
__global__ __launch_bounds__(512, 2) void attn_fused(
    const ushort* __restrict__ Qb, const ushort* __restrict__ Kb,
    const _Float16* __restrict__ Vt, ushort* __restrict__ attn,
    float* __restrict__ avgp)
{
  __shared__ _Float16 sc[16 * 2048];   // 64 KB, column-swizzled: col ^ ((row&7)<<3)
  __shared__ float scr[1024];          // 4 KB PV partial-reduction scratch
  __shared__ float invl[16];

  const int qt = blockIdx.x;      // 0..127
  const int b  = blockIdx.y;      // 0..3
  const int tid = threadIdx.x;
  const int lane = tid & 63;
  const int w = tid >> 6;         // wave 0..7
  const int m = lane & 15;
  const int kq = lane >> 4;       // frag k-chunk == C-layout row group
  const int t0 = qt * 16;

  // per-thread avg accumulator: rows w*2+u (u=0..1), cols (c*64+lane)*8+j
  f32x8 av[2][4];
#pragma unroll
  for (int u = 0; u < 2; u++)
#pragma unroll
    for (int c = 0; c < 4; c++) av[u][c] = (f32x8)(0.f);

  for (int h = 0; h < HH; ++h) {
    const size_t bh = (size_t)b * HH + h;

    // ---- Q fragments (bf16), Q pre-scaled by 1/8
    const ushort* qp = Qb + (bh * TT + t0) * DD;
    s16x8 q0 = *(const s16x8*)&qp[(size_t)m * DD + kq * 8];
    s16x8 q1 = *(const s16x8*)&qp[(size_t)m * DD + 32 + kq * 8];

    // ---- QK^T: wave w owns k-tiles w*16 .. w*16+15 (keys w*256..+255)
    const ushort* kbase = Kb + bh * TT * DD;
#pragma unroll 4
    for (int i = 0; i < 16; ++i) {
      int nt = w * 16 + i;
      const ushort* kr = kbase + (size_t)(nt * 16 + m) * DD + kq * 8;
      s16x8 a0 = *(const s16x8*)kr;
      s16x8 a1 = *(const s16x8*)(kr + 32);
      f32x4 c0 = {0.f, 0.f, 0.f, 0.f};
      c0 = MFMA_BF16(a0, q0, c0);
      c0 = MFMA_BF16(a1, q1, c0);
      // lane holds S[k = nt*16 + kq*4 + e][q = m] -> 4 k-consecutive f16, packed write
      int ksw = (nt * 16 + kq * 4) ^ ((m & 7) << 3);
      h4 p0;
#pragma unroll
      for (int e = 0; e < 4; e++) p0[e] = (_Float16)c0[e];
      *(h4*)&sc[(size_t)m * 2048 + ksw] = p0;
    }
    __syncthreads();

    // ---- softmax: wave w owns rows w*2, w*2+1; store UNNORMALIZED exp back;
    //      fold normalized-weight sum into av[] registers. v[] reused in place
    //      (raw scores -> exp f16) to keep peak VGPR below the 128 cap.
#pragma unroll
    for (int u = 0; u < 2; ++u) {
      int r = w * 2 + u;
      _Float16* rp = &sc[(size_t)r * 2048];
      int xr = (r & 7) << 3;
      float mx = -3e38f;
      h8 v[4];
#pragma unroll
      for (int c = 0; c < 4; ++c) {
        v[c] = *(const h8*)&rp[((c * 64 + lane) * 8) ^ xr];
#pragma unroll
        for (int j = 0; j < 8; j++) mx = fmaxf(mx, (float)v[c][j]);
      }
#pragma unroll
      for (int o = 32; o; o >>= 1) mx = fmaxf(mx, __shfl_xor(mx, o));
      float l = 0.f;
#pragma unroll
      for (int c = 0; c < 4; ++c) {
#pragma unroll
        for (int j = 0; j < 8; j++) { float e = __expf((float)v[c][j] - mx); l += e; v[c][j] = (_Float16)e; }
        *(h8*)&rp[((c * 64 + lane) * 8) ^ xr] = v[c];
      }
#pragma unroll
      for (int o = 32; o; o >>= 1) l += __shfl_xor(l, o);
      float inv = 1.0f / l;
      if (lane == 0) invl[r] = inv;
#pragma unroll
      for (int c = 0; c < 4; ++c)
#pragma unroll
        for (int j = 0; j < 8; j++)
          av[u][c][j] += (float)v[c][j] * inv;
    }
    __syncthreads();

    // ---- PV: wave = (d-tile, k-half); V (f16) read once per block-head
    {
      int dtl = w & 3, kh = w >> 2;
      const _Float16* vb = Vt + bh * DD * TT + (size_t)(dtl * 16 + m) * TT + kh * 1024 + kq * 8;
      const _Float16* ap = &sc[(size_t)m * 2048];
      int xr = (m & 7) << 3;
      f32x4 acc0 = {0.f, 0.f, 0.f, 0.f};
#pragma unroll 4
      for (int s = 0; s < 32; ++s) {
        int ksw = (kh * 1024 + s * 32 + kq * 8) ^ xr;
        h8 bv = *(const h8*)(vb + s * 32);
        h8 a0 = *(const h8*)&ap[ksw];
        acc0 = MFMA_F16(a0, bv, acc0);
      }
      if (kh == 1) {
#pragma unroll
        for (int e = 0; e < 4; e++)
          scr[dtl * 256 + (kq * 4 + e) * 16 + m] = acc0[e];
      }
      __syncthreads();
      if (kh == 0) {
#pragma unroll
        for (int e = 0; e < 4; e++) {
          int ql = kq * 4 + e;
          float v0 = (acc0[e] + scr[dtl * 256 + ql * 16 + m]) * invl[ql];
          attn[((size_t)(t0 + ql) * BB + b) * EE + h * DD + dtl * 16 + m] = f2bf(v0);
        }
      }
    }
    __syncthreads();   // sc/scr reads done before next head overwrites
  }

  // ---- write avg once: row t0 + w*2+u, cols (c*64+lane)*8 .. +7
#pragma unroll
  for (int u = 0; u < 2; ++u) {
    float* gp = avgp + ((size_t)b * TT + t0 + w * 2 + u) * TT;
#pragma unroll
    for (int c = 0; c < 4; ++c) {
      int cb = (c * 64 + lane) * 8;
      float4 o0 = {av[u][c][0] * 0.0625f, av[u][c][1] * 0.0625f,
                   av[u][c][2] * 0.0625f, av[u][c][3] * 0.0625f};
      float4 o1 = {av[u][c][4] * 0.0625f, av[u][c][5] * 0.0625f,
                   av[u][c][6] * 0.0625f, av[u][c][7] * 0.0625f};
      ((float4*)(gp + cb))[0] = o0;
      ((float4*)(gp + cb))[1] = o1;
    }
  }
}

// ---------------------------------------------------------------- output projection
__global__ __launch_bounds__(256) void gemm_out(
    const ushort* __restrict__ A, const ushort* __restrict__ W,
    const float* __restrict__ bias, float* __restrict__ out)
{
  __shared__ ushort As[128 * 32];
  __shared__ ushort Bs[128 * 32];
  const int K = EE;
  int tid = threadIdx.x;
  int bn = blockIdx.x, bm = blockIdx.y;
  int brow = bm * 128, bcol = bn * 128;
  int lane = tid & 63, wid = tid >> 6;
  int wm = wid >> 1, wn = wid & 1;
  int lr = lane & 15, kg = lane >> 4;

  f32x4 zero = {0.f, 0.f, 0.f, 0.f};
  f32x4 acc[4][4];
#pragma unroll
  for (int i = 0; i < 4; i++)
#pragma unroll
    for (int j = 0; j < 4; j++) acc[i][j] = zero;

  int r0 = tid >> 2, c0 = (tid & 3) * 8;
  const ushort* Abase = A + (size_t)brow * K;
  const ushort* Wbase = W + (size_t)bcol * K;

  for (int k0 = 0; k0 < K; k0 += 32) {
    __syncthreads();
    GL2L(Abase + (size_t)r0 * K + k0 + c0,        &As[tid * 8]);
    GL2L(Abase + (size_t)(r0 + 64) * K + k0 + c0, &As[(tid + 256) * 8]);
    GL2L(Wbase + (size_t)r0 * K + k0 + c0,        &Bs[tid * 8]);
    GL2L(Wbase + (size_t)(r0 + 64) * K + k0 + c0, &Bs[(tid + 256) * 8]);
    __syncthreads();
    s16x8 af[4], bfr[4];
#pragma unroll
    for (int i = 0; i < 4; i++) af[i]  = *(const s16x8*)&As[(wm * 64 + i * 16 + lr) * 32 + kg * 8];
#pragma unroll
    for (int j = 0; j < 4; j++) bfr[j] = *(const s16x8*)&Bs[(wn * 64 + j * 16 + lr) * 32 + kg * 8];
#pragma unroll
    for (int i = 0; i < 4; i++)
#pragma unroll
      for (int j = 0; j < 4; j++)
        acc[i][j] = MFMA_BF16(af[i], bfr[j], acc[i][j]);
  }

#pragma unroll
  for (int i = 0; i < 4; i++)
#pragma unroll
    for (int j = 0; j < 4; j++) {
      int n = bcol + wn * 64 + j * 16 + lr;
      float bv = bias[n];
#pragma unroll
      for (int e = 0; e < 4; e++) {
        int m = brow + wm * 64 + i * 16 + kg * 4 + e;
        out[(size_t)m * EE + n] = acc[i][j][e] + bv;
      }
    }
}

// ---------------------------------------------------------------- launch
extern "C" void kernel_launch(void* const* d_in, const int* in_sizes, int n_in,
                              void* d_out, int out_size, void* d_ws, size_t ws_size,
                              hipStream_t stream) {
  const float* x  = (const float*)d_in[0];
  const float* w1 = (const float*)d_in[1];
  const float* b1 = (const float*)d_in[2];
  const float* w2 = (const float*)d_in[3];
  const float* b2 = (const float*)d_in[4];
  float* out = (float*)d_out;
  float* avg = out + (size_t)MR * EE;

  char* p = (char*)d_ws;
  ushort* Xb   = (ushort*)p; p += (size_t)MR * EE * 2;
  ushort* W1b  = (ushort*)p; p += (size_t)3 * EE * EE * 2;
  ushort* W2b  = (ushort*)p; p += (size_t)EE * EE * 2;
  ushort* Qb   = (ushort*)p; p += (size_t)BB * HH * TT * DD * 2;
  ushort* Kb   = (ushort*)p; p += (size_t)BB * HH * TT * DD * 2;
  ushort* Vt   = (ushort*)p; p += (size_t)BB * HH * TT * DD * 2;
  ushort* attn = (ushort*)p; p += (size_t)MR * EE * 2;
  (void)ws_size;

  cast_f32_bf16<<<1024, 256, 0, stream>>>(x,  Xb,  MR * EE / 4);
  cast_f32_bf16<<<512,  256, 0, stream>>>(w1, W1b, 3 * EE * EE / 4);
  cast_f32_bf16<<<256,  256, 0, stream>>>(w2, W2b, EE * EE / 4);
  gemm_qkv<<<dim3(24, 64), 256, 0, stream>>>(Xb, W1b, b1, Qb, Kb, Vt);
  attn_fused<<<dim3(TT / 16, BB), 512, 0, stream>>>(Qb, Kb, (const _Float16*)Vt, attn, avg);
  gemm_out<<<dim3(8, 64), 256, 0, stream>>>(attn, W2b, b2, out);
}

// Round 6
// 685.437 us; speedup vs baseline: 1.0872x; 1.0400x over previous
//
#include <hip/hip_runtime.h>
#include <hip/hip_bf16.h>
#include <cstdint>
#include <cstddef>

typedef __attribute__((ext_vector_type(8))) short s16x8;
typedef __attribute__((ext_vector_type(4))) float f32x4;
typedef __attribute__((ext_vector_type(8))) _Float16 h8;
typedef __attribute__((ext_vector_type(4))) _Float16 h4;

#define TT 2048
#define BB 4
#define EE 1024
#define HH 16
#define DD 64
#define MR 8192   // T*B rows

#define MFMA_BF16(a,b,c) __builtin_amdgcn_mfma_f32_16x16x32_bf16(a,b,c,0,0,0)
#define MFMA_F16(a,b,c)  __builtin_amdgcn_mfma_f32_16x16x32_f16(a,b,c,0,0,0)

__device__ __forceinline__ ushort f2bf(float f) {
  uint32_t u = __float_as_uint(f);
  u += 0x7fffu + ((u >> 16) & 1u);   // RNE
  return (ushort)(u >> 16);
}

// global -> LDS async copy, 16B per lane. LDS dest must be wave-uniform base + lane*16.
#define GL2L(g, l) __builtin_amdgcn_global_load_lds( \
    (__attribute__((address_space(1))) void*)(g), \
    (__attribute__((address_space(3))) void*)(l), 16, 0, 0)

// ---------------------------------------------------------------- cast fp32->bf16
__global__ void cast_f32_bf16(const float* __restrict__ in, ushort* __restrict__ out, int n4) {
  int stride = gridDim.x * blockDim.x;
  for (int i = blockIdx.x * blockDim.x + threadIdx.x; i < n4; i += stride) {
    float4 v = ((const float4*)in)[i];
    ushort4 o;
    o.x = f2bf(v.x); o.y = f2bf(v.y); o.z = f2bf(v.z); o.w = f2bf(v.w);
    ((ushort4*)out)[i] = o;
  }
}

// ---------------------------------------------------------------- QKV projection
// C[m][n] = sum_k A[m][k]*W[n][k] + bias[n];  m=(t*4+b), n = sec*1024 + h*64 + d
// Q scaled by 0.125 -> bf16 [b][h][t][d]; K -> bf16 same; V -> f16 transposed [b][h][d][t].
__global__ __launch_bounds__(256) void gemm_qkv(
    const ushort* __restrict__ A, const ushort* __restrict__ W,
    const float* __restrict__ bias,
    ushort* __restrict__ Qb, ushort* __restrict__ Kb, ushort* __restrict__ Vt)
{
  __shared__ ushort As[128 * 32];
  __shared__ ushort Bs[128 * 32];
  const int K = EE;
  int tid = threadIdx.x;
  int bn = blockIdx.x, bm = blockIdx.y;
  int brow = bm * 128, bcol = bn * 128;
  int lane = tid & 63, wid = tid >> 6;
  int wm = wid >> 1, wn = wid & 1;
  int lr = lane & 15, kg = lane >> 4;

  f32x4 zero = {0.f, 0.f, 0.f, 0.f};
  f32x4 acc[4][4];
#pragma unroll
  for (int i = 0; i < 4; i++)
#pragma unroll
    for (int j = 0; j < 4; j++) acc[i][j] = zero;

  int r0 = tid >> 2, c0 = (tid & 3) * 8;
  const ushort* Abase = A + (size_t)brow * K;
  const ushort* Wbase = W + (size_t)bcol * K;

  for (int k0 = 0; k0 < K; k0 += 32) {
    __syncthreads();
    GL2L(Abase + (size_t)r0 * K + k0 + c0,        &As[tid * 8]);
    GL2L(Abase + (size_t)(r0 + 64) * K + k0 + c0, &As[(tid + 256) * 8]);
    GL2L(Wbase + (size_t)r0 * K + k0 + c0,        &Bs[tid * 8]);
    GL2L(Wbase + (size_t)(r0 + 64) * K + k0 + c0, &Bs[(tid + 256) * 8]);
    __syncthreads();
    s16x8 af[4], bfr[4];
#pragma unroll
    for (int i = 0; i < 4; i++) af[i]  = *(const s16x8*)&As[(wm * 64 + i * 16 + lr) * 32 + kg * 8];
#pragma unroll
    for (int j = 0; j < 4; j++) bfr[j] = *(const s16x8*)&Bs[(wn * 64 + j * 16 + lr) * 32 + kg * 8];
#pragma unroll
    for (int i = 0; i < 4; i++)
#pragma unroll
      for (int j = 0; j < 4; j++)
        acc[i][j] = MFMA_BF16(af[i], bfr[j], acc[i][j]);
  }

#pragma unroll
  for (int i = 0; i < 4; i++)
#pragma unroll
    for (int j = 0; j < 4; j++) {
      int n = bcol + wn * 64 + j * 16 + lr;
      float bv = bias[n];
      int sec = n >> 10;
      int hd = n & 1023;
      int h = hd >> 6, d = hd & 63;
#pragma unroll
      for (int e = 0; e < 4; e++) {
        int m = brow + wm * 64 + i * 16 + kg * 4 + e;
        int t = m >> 2, b = m & 3;
        float v = acc[i][j][e] + bv;
        size_t hoff = (size_t)(b * HH + h);
        if (sec == 0)      Qb[(hoff * TT + t) * DD + d] = f2bf(v * 0.125f);
        else if (sec == 1) Kb[(hoff * TT + t) * DD + d] = f2bf(v);
        else { _Float16 hv = (_Float16)v; Vt[(hoff * DD + d) * TT + t] = *(ushort*)&hv; }
      }
    }
}

// ---------------------------------------------------------------- fused attention
// block = (qt, b): 16 q-rows x all 2048 keys x all 16 heads. 512 thr.
// Per head: QK^T (swapped mfma -> packed LDS writes, XOR swizzle), 3-sweep
// softmax over LDS (max / exp+store / reload+accumulate-avg-in-f16-regs),
// PV f16 MFMA with (d-tile, k-half) waves + LDS partial reduction.
// launch_bounds(512,4): forces total (VGPR+AGPR) <= 128/wave so 2 blocks/CU
// co-reside (LDS 70KB also allows 2). Live state kept < 128: av is packed
// f16 (32 regs), softmax keeps one h8 chunk live at a time.
__global__ __launch_bounds__(512, 4) void attn_fused(
    const ushort* __restrict__ Qb, const ushort* __restrict__ Kb,
    const _Float16* __restrict__ Vt, ushort* __restrict__ attn,
    float* __restrict__ avgp)
{
  __shared__ _Float16 sc[16 * 2048];   // 64 KB, column-swizzled: col ^ ((row&7)<<3)
  __shared__ float scr[1024];          // 4 KB PV partial-reduction scratch
  __shared__ float invl[16];

  const int qt = blockIdx.x;      // 0..127
  const int b  = blockIdx.y;      // 0..3
  const int tid = threadIdx.x;
  const int lane = tid & 63;
  const int w = tid >> 6;         // wave 0..7
  const int m = lane & 15;
  const int kq = lane >> 4;       // frag k-chunk == C-layout row group
  const int t0 = qt * 16;

  // per-thread avg accumulator, PACKED f16: rows w*2+u, cols (c*64+lane)*8+j
  h8 av[2][4];
#pragma unroll
  for (int u = 0; u < 2; u++)
#pragma unroll
    for (int c = 0; c < 4; c++)
#pragma unroll
      for (int j = 0; j < 8; j++) av[u][c][j] = (_Float16)0.f;

  for (int h = 0; h < HH; ++h) {
    const size_t bh = (size_t)b * HH + h;

    // ---- Q fragments (bf16), Q pre-scaled by 1/8
    const ushort* qp = Qb + (bh * TT + t0) * DD;
    s16x8 q0 = *(const s16x8*)&qp[(size_t)m * DD + kq * 8];
    s16x8 q1 = *(const s16x8*)&qp[(size_t)m * DD + 32 + kq * 8];

    // ---- QK^T: wave w owns k-tiles w*16 .. w*16+15 (keys w*256..+255)
    const ushort* kbase = Kb + bh * TT * DD;
#pragma unroll 4
    for (int i = 0; i < 16; ++i) {
      int nt = w * 16 + i;
      const ushort* kr = kbase + (size_t)(nt * 16 + m) * DD + kq * 8;
      s16x8 a0 = *(const s16x8*)kr;
      s16x8 a1 = *(const s16x8*)(kr + 32);
      f32x4 c0 = {0.f, 0.f, 0.f, 0.f};
      c0 = MFMA_BF16(a0, q0, c0);
      c0 = MFMA_BF16(a1, q1, c0);
      // lane holds S[k = nt*16 + kq*4 + e][q = m] -> 4 k-consecutive f16, packed write
      int ksw = (nt * 16 + kq * 4) ^ ((m & 7) << 3);
      h4 p0;
#pragma unroll
      for (int e = 0; e < 4; e++) p0[e] = (_Float16)c0[e];
      *(h4*)&sc[(size_t)m * 2048 + ksw] = p0;
    }
    __syncthreads();

    // ---- softmax: wave w owns rows w*2, w*2+1. 3 sweeps over the LDS row so
    //      at most one h8 chunk is live (register trim).
#pragma unroll
    for (int u = 0; u < 2; ++u) {
      int r = w * 2 + u;
      _Float16* rp = &sc[(size_t)r * 2048];
      int xr = (r & 7) << 3;
      float mx = -3e38f;
#pragma unroll
      for (int c = 0; c < 4; ++c) {
        h8 t = *(const h8*)&rp[((c * 64 + lane) * 8) ^ xr];
#pragma unroll
        for (int j = 0; j < 8; j++) mx = fmaxf(mx, (float)t[j]);
      }
#pragma unroll
      for (int o = 32; o; o >>= 1) mx = fmaxf(mx, __shfl_xor(mx, o));
      float l = 0.f;
#pragma unroll
      for (int c = 0; c < 4; ++c) {
        h8 t = *(const h8*)&rp[((c * 64 + lane) * 8) ^ xr];
        h8 e;
#pragma unroll
        for (int j = 0; j < 8; j++) { float ef = __expf((float)t[j] - mx); l += ef; e[j] = (_Float16)ef; }
        *(h8*)&rp[((c * 64 + lane) * 8) ^ xr] = e;
      }
#pragma unroll
      for (int o = 32; o; o >>= 1) l += __shfl_xor(l, o);
      float inv = 1.0f / l;
      if (lane == 0) invl[r] = inv;
      _Float16 hinv = (_Float16)inv;
#pragma unroll
      for (int c = 0; c < 4; ++c) {
        h8 e = *(const h8*)&rp[((c * 64 + lane) * 8) ^ xr];
        av[u][c] += e * hinv;           // v_pk_mul/add_f16
      }
    }
    __syncthreads();

    // ---- PV: wave = (d-tile, k-half); V (f16) read once per block-head.
    //      Two independent MFMA chains halve the serial dependency depth.
    {
      int dtl = w & 3, kh = w >> 2;
      const _Float16* vb = Vt + bh * DD * TT + (size_t)(dtl * 16 + m) * TT + kh * 1024 + kq * 8;
      const _Float16* ap = &sc[(size_t)m * 2048];
      int xr = (m & 7) << 3;
      f32x4 accA = {0.f, 0.f, 0.f, 0.f};
      f32x4 accB = {0.f, 0.f, 0.f, 0.f};
#pragma unroll 2
      for (int s = 0; s < 32; s += 2) {
        int ksw0 = (kh * 1024 + s * 32 + kq * 8) ^ xr;
        int ksw1 = (kh * 1024 + (s + 1) * 32 + kq * 8) ^ xr;
        h8 bv0 = *(const h8*)(vb + s * 32);
        h8 bv1 = *(const h8*)(vb + (s + 1) * 32);
        h8 a0 = *(const h8*)&ap[ksw0];
        h8 a1 = *(const h8*)&ap[ksw1];
        accA = MFMA_F16(a0, bv0, accA);
        accB = MFMA_F16(a1, bv1, accB);
      }
      if (kh == 1) {
#pragma unroll
        for (int e = 0; e < 4; e++)
          scr[dtl * 256 + (kq * 4 + e) * 16 + m] = accA[e] + accB[e];
      }
      __syncthreads();
      if (kh == 0) {
#pragma unroll
        for (int e = 0; e < 4; e++) {
          int ql = kq * 4 + e;
          float v0 = (accA[e] + accB[e] + scr[dtl * 256 + ql * 16 + m]) * invl[ql];
          attn[((size_t)(t0 + ql) * BB + b) * EE + h * DD + dtl * 16 + m] = f2bf(v0);
        }
      }
    }
    __syncthreads();   // sc/scr reads done before next head overwrites
  }

  // ---- write avg once: row t0 + w*2+u, cols (c*64+lane)*8 .. +7
#pragma unroll
  for (int u = 0; u < 2; ++u) {
    float* gp = avgp + ((size_t)b * TT + t0 + w * 2 + u) * TT;
#pragma unroll
    for (int c = 0; c < 4; ++c) {
      int cb = (c * 64 + lane) * 8;
      float4 o0 = {(float)av[u][c][0] * 0.0625f, (float)av[u][c][1] * 0.0625f,
                   (float)av[u][c][2] * 0.0625f, (float)av[u][c][3] * 0.0625f};
      float4 o1 = {(float)av[u][c][4] * 0.0625f, (float)av[u][c][5] * 0.0625f,
                   (float)av[u][c][6] * 0.0625f, (float)av[u][c][7] * 0.0625f};
      ((float4*)(gp + cb))[0] = o0;
      ((float4*)(gp + cb))[1] = o1;
    }
  }
}

// ---------------------------------------------------------------- output projection
__global__ __launch_bounds__(256) void gemm_out(
    const ushort* __restrict__ A, const ushort* __restrict__ W,
    const float* __restrict__ bias, float* __restrict__ out)
{
  __shared__ ushort As[128 * 32];
  __shared__ ushort Bs[128 * 32];
  const int K = EE;
  int tid = threadIdx.x;
  int bn = blockIdx.x, bm = blockIdx.y;
  int brow = bm * 128, bcol = bn * 128;
  int lane = tid & 63, wid = tid >> 6;
  int wm = wid >> 1, wn = wid & 1;
  int lr = lane & 15, kg = lane >> 4;

  f32x4 zero = {0.f, 0.f, 0.f, 0.f};
  f32x4 acc[4][4];
#pragma unroll
  for (int i = 0; i < 4; i++)
#pragma unroll
    for (int j = 0; j < 4; j++) acc[i][j] = zero;

  int r0 = tid >> 2, c0 = (tid & 3) * 8;
  const ushort* Abase = A + (size_t)brow * K;
  const ushort* Wbase = W + (size_t)bcol * K;

  for (int k0 = 0; k0 < K; k0 += 32) {
    __syncthreads();
    GL2L(Abase + (size_t)r0 * K + k0 + c0,        &As[tid * 8]);
    GL2L(Abase + (size_t)(r0 + 64) * K + k0 + c0, &As[(tid + 256) * 8]);
    GL2L(Wbase + (size_t)r0 * K + k0 + c0,        &Bs[tid * 8]);
    GL2L(Wbase + (size_t)(r0 + 64) * K + k0 + c0, &Bs[(tid + 256) * 8]);
    __syncthreads();
    s16x8 af[4], bfr[4];
#pragma unroll
    for (int i = 0; i < 4; i++) af[i]  = *(const s16x8*)&As[(wm * 64 + i * 16 + lr) * 32 + kg * 8];
#pragma unroll
    for (int j = 0; j < 4; j++) bfr[j] = *(const s16x8*)&Bs[(wn * 64 + j * 16 + lr) * 32 + kg * 8];
#pragma unroll
    for (int i = 0; i < 4; i++)
#pragma unroll
      for (int j = 0; j < 4; j++)
        acc[i][j] = MFMA_BF16(af[i], bfr[j], acc[i][j]);
  }

#pragma unroll
  for (int i = 0; i < 4; i++)
#pragma unroll
    for (int j = 0; j < 4; j++) {
      int n = bcol + wn * 64 + j * 16 + lr;
      float bv = bias[n];
#pragma unroll
      for (int e = 0; e < 4; e++) {
        int m = brow + wm * 64 + i * 16 + kg * 4 + e;
        out[(size_t)m * EE + n] = acc[i][j][e] + bv;
      }
    }
}

// ---------------------------------------------------------------- launch
extern "C" void kernel_launch(void* const* d_in, const int* in_sizes, int n_in,
                              void* d_out, int out_size, void* d_ws, size_t ws_size,
                              hipStream_t stream) {
  const float* x  = (const float*)d_in[0];
  const float* w1 = (const float*)d_in[1];
  const float* b1 = (const float*)d_in[2];
  const float* w2 = (const float*)d_in[3];
  const float* b2 = (const float*)d_in[4];
  float* out = (float*)d_out;
  float* avg = out + (size_t)MR * EE;

  char* p = (char*)d_ws;
  ushort* Xb   = (ushort*)p; p += (size_t)MR * EE * 2;
  ushort* W1b  = (ushort*)p; p += (size_t)3 * EE * EE * 2;
  ushort* W2b  = (ushort*)p; p += (size_t)EE * EE * 2;
  ushort* Qb   = (ushort*)p; p += (size_t)BB * HH * TT * DD * 2;
  ushort* Kb   = (ushort*)p; p += (size_t)BB * HH * TT * DD * 2;
  ushort* Vt   = (ushort*)p; p += (size_t)BB * HH * TT * DD * 2;
  ushort* attn = (ushort*)p; p += (size_t)MR * EE * 2;
  (void)ws_size;

  cast_f32_bf16<<<1024, 256, 0, stream>>>(x,  Xb,  MR * EE / 4);
  cast_f32_bf16<<<512,  256, 0, stream>>>(w1, W1b, 3 * EE * EE / 4);
  cast_f32_bf16<<<256,  256, 0, stream>>>(w2, W2b, EE * EE / 4);
  gemm_qkv<<<dim3(24, 64), 256, 0, stream>>>(Xb, W1b, b1, Qb, Kb, Vt);
  attn_fused<<<dim3(TT / 16, BB), 512, 0, stream>>>(Qb, Kb, (const _Float16*)Vt, attn, avg);
  gemm_out<<<dim3(8, 64), 256, 0, stream>>>(attn, W2b, b2, out);
}

// Round 7
// 685.335 us; speedup vs baseline: 1.0874x; 1.0001x over previous
//
#include <hip/hip_runtime.h>
#include <hip/hip_bf16.h>
#include <cstdint>
#include <cstddef>

typedef __attribute__((ext_vector_type(8))) short s16x8;
typedef __attribute__((ext_vector_type(4))) float f32x4;
typedef __attribute__((ext_vector_type(8))) _Float16 h8;
typedef __attribute__((ext_vector_type(4))) _Float16 h4;

#define TT 2048
#define BB 4
#define EE 1024
#define HH 16
#define DD 64
#define MR 8192   // T*B rows

#define MFMA_BF16(a,b,c) __builtin_amdgcn_mfma_f32_16x16x32_bf16(a,b,c,0,0,0)
#define MFMA_F16(a,b,c)  __builtin_amdgcn_mfma_f32_16x16x32_f16(a,b,c,0,0,0)

__device__ __forceinline__ ushort f2bf(float f) {
  uint32_t u = __float_as_uint(f);
  u += 0x7fffu + ((u >> 16) & 1u);   // RNE
  return (ushort)(u >> 16);
}

// global -> LDS async copy, 16B per lane. LDS dest must be wave-uniform base + lane*16.
#define GL2L(g, l) __builtin_amdgcn_global_load_lds( \
    (__attribute__((address_space(1))) void*)(g), \
    (__attribute__((address_space(3))) void*)(l), 16, 0, 0)

// ---------------------------------------------------------------- cast fp32->bf16
__global__ void cast_f32_bf16(const float* __restrict__ in, ushort* __restrict__ out, int n4) {
  int stride = gridDim.x * blockDim.x;
  for (int i = blockIdx.x * blockDim.x + threadIdx.x; i < n4; i += stride) {
    float4 v = ((const float4*)in)[i];
    ushort4 o;
    o.x = f2bf(v.x); o.y = f2bf(v.y); o.z = f2bf(v.z); o.w = f2bf(v.w);
    ((ushort4*)out)[i] = o;
  }
}

// ---------------------------------------------------------------- QKV projection
// C[m][n] = sum_k A[m][k]*W[n][k] + bias[n];  m=(t*4+b), n = sec*1024 + h*64 + d
// Q scaled by 0.125 -> bf16 [b][h][t][d]; K -> bf16 same; V -> f16 transposed [b][h][d][t].
__global__ __launch_bounds__(256) void gemm_qkv(
    const ushort* __restrict__ A, const ushort* __restrict__ W,
    const float* __restrict__ bias,
    ushort* __restrict__ Qb, ushort* __restrict__ Kb, ushort* __restrict__ Vt)
{
  __shared__ ushort As[128 * 32];
  __shared__ ushort Bs[128 * 32];
  const int K = EE;
  int tid = threadIdx.x;
  int bn = blockIdx.x, bm = blockIdx.y;
  int brow = bm * 128, bcol = bn * 128;
  int lane = tid & 63, wid = tid >> 6;
  int wm = wid >> 1, wn = wid & 1;
  int lr = lane & 15, kg = lane >> 4;

  f32x4 zero = {0.f, 0.f, 0.f, 0.f};
  f32x4 acc[4][4];
#pragma unroll
  for (int i = 0; i < 4; i++)
#pragma unroll
    for (int j = 0; j < 4; j++) acc[i][j] = zero;

  int r0 = tid >> 2, c0 = (tid & 3) * 8;
  const ushort* Abase = A + (size_t)brow * K;
  const ushort* Wbase = W + (size_t)bcol * K;

  for (int k0 = 0; k0 < K; k0 += 32) {
    __syncthreads();
    GL2L(Abase + (size_t)r0 * K + k0 + c0,        &As[tid * 8]);
    GL2L(Abase + (size_t)(r0 + 64) * K + k0 + c0, &As[(tid + 256) * 8]);
    GL2L(Wbase + (size_t)r0 * K + k0 + c0,        &Bs[tid * 8]);
    GL2L(Wbase + (size_t)(r0 + 64) * K + k0 + c0, &Bs[(tid + 256) * 8]);
    __syncthreads();
    s16x8 af[4], bfr[4];
#pragma unroll
    for (int i = 0; i < 4; i++) af[i]  = *(const s16x8*)&As[(wm * 64 + i * 16 + lr) * 32 + kg * 8];
#pragma unroll
    for (int j = 0; j < 4; j++) bfr[j] = *(const s16x8*)&Bs[(wn * 64 + j * 16 + lr) * 32 + kg * 8];
#pragma unroll
    for (int i = 0; i < 4; i++)
#pragma unroll
      for (int j = 0; j < 4; j++)
        acc[i][j] = MFMA_BF16(af[i], bfr[j], acc[i][j]);
  }

#pragma unroll
  for (int i = 0; i < 4; i++)
#pragma unroll
    for (int j = 0; j < 4; j++) {
      int n = bcol + wn * 64 + j * 16 + lr;
      float bv = bias[n];
      int sec = n >> 10;
      int hd = n & 1023;
      int h = hd >> 6, d = hd & 63;
#pragma unroll
      for (int e = 0; e < 4; e++) {
        int m = brow + wm * 64 + i * 16 + kg * 4 + e;
        int t = m >> 2, b = m & 3;
        float v = acc[i][j][e] + bv;
        size_t hoff = (size_t)(b * HH + h);
        if (sec == 0)      Qb[(hoff * TT + t) * DD + d] = f2bf(v * 0.125f);
        else if (sec == 1) Kb[(hoff * TT + t) * DD + d] = f2bf(v);
        else { _Float16 hv = (_Float16)v; Vt[(hoff * DD + d) * TT + t] = *(ushort*)&hv; }
      }
    }
}

// ---------------------------------------------------------------- fused attention
// block = (qt, b): 16 q-rows x all 2048 keys x all 16 heads. 512 thr.
// Per head: QK^T (swapped mfma -> packed LDS writes, XOR swizzle), 3-sweep
// softmax over LDS (max / exp+store / reload+accumulate-avg-in-f16-regs),
// PV f16 MFMA with (d-tile, k-half) waves + LDS partial reduction.
// amdgpu_waves_per_eu(4): demand >=4 waves/SIMD => VGPR+AGPR total <= 128/wave
// (unified file). Audited live state ~100 regs, so this should NOT spill
// (unlike launch_bounds(512,4), which this toolchain maps to a 64-VGPR cap).
__attribute__((amdgpu_waves_per_eu(4)))
__global__ __launch_bounds__(512) void attn_fused(
    const ushort* __restrict__ Qb, const ushort* __restrict__ Kb,
    const _Float16* __restrict__ Vt, ushort* __restrict__ attn,
    float* __restrict__ avgp)
{
  __shared__ _Float16 sc[16 * 2048];   // 64 KB, column-swizzled: col ^ ((row&7)<<3)
  __shared__ float scr[1024];          // 4 KB PV partial-reduction scratch
  __shared__ float invl[16];

  const int qt = blockIdx.x;      // 0..127
  const int b  = blockIdx.y;      // 0..3
  const int tid = threadIdx.x;
  const int lane = tid & 63;
  const int w = tid >> 6;         // wave 0..7
  const int m = lane & 15;
  const int kq = lane >> 4;       // frag k-chunk == C-layout row group
  const int t0 = qt * 16;

  // per-thread avg accumulator, PACKED f16: rows w*2+u, cols (c*64+lane)*8+j
  h8 av[2][4];
#pragma unroll
  for (int u = 0; u < 2; u++)
#pragma unroll
    for (int c = 0; c < 4; c++)
#pragma unroll
      for (int j = 0; j < 8; j++) av[u][c][j] = (_Float16)0.f;

  for (int h = 0; h < HH; ++h) {
    const size_t bh = (size_t)b * HH + h;

    // ---- Q fragments (bf16), Q pre-scaled by 1/8
    const ushort* qp = Qb + (bh * TT + t0) * DD;
    s16x8 q0 = *(const s16x8*)&qp[(size_t)m * DD + kq * 8];
    s16x8 q1 = *(const s16x8*)&qp[(size_t)m * DD + 32 + kq * 8];

    // ---- QK^T: wave w owns k-tiles w*16 .. w*16+15 (keys w*256..+255)
    const ushort* kbase = Kb + bh * TT * DD;
#pragma unroll 4
    for (int i = 0; i < 16; ++i) {
      int nt = w * 16 + i;
      const ushort* kr = kbase + (size_t)(nt * 16 + m) * DD + kq * 8;
      s16x8 a0 = *(const s16x8*)kr;
      s16x8 a1 = *(const s16x8*)(kr + 32);
      f32x4 c0 = {0.f, 0.f, 0.f, 0.f};
      c0 = MFMA_BF16(a0, q0, c0);
      c0 = MFMA_BF16(a1, q1, c0);
      // lane holds S[k = nt*16 + kq*4 + e][q = m] -> 4 k-consecutive f16, packed write
      int ksw = (nt * 16 + kq * 4) ^ ((m & 7) << 3);
      h4 p0;
#pragma unroll
      for (int e = 0; e < 4; e++) p0[e] = (_Float16)c0[e];
      *(h4*)&sc[(size_t)m * 2048 + ksw] = p0;
    }
    __syncthreads();

    // ---- softmax: wave w owns rows w*2, w*2+1. 3 sweeps over the LDS row so
    //      at most one h8 chunk is live (register trim).
#pragma unroll
    for (int u = 0; u < 2; ++u) {
      int r = w * 2 + u;
      _Float16* rp = &sc[(size_t)r * 2048];
      int xr = (r & 7) << 3;
      float mx = -3e38f;
#pragma unroll
      for (int c = 0; c < 4; ++c) {
        h8 t = *(const h8*)&rp[((c * 64 + lane) * 8) ^ xr];
#pragma unroll
        for (int j = 0; j < 8; j++) mx = fmaxf(mx, (float)t[j]);
      }
#pragma unroll
      for (int o = 32; o; o >>= 1) mx = fmaxf(mx, __shfl_xor(mx, o));
      float l = 0.f;
#pragma unroll
      for (int c = 0; c < 4; ++c) {
        h8 t = *(const h8*)&rp[((c * 64 + lane) * 8) ^ xr];
        h8 e;
#pragma unroll
        for (int j = 0; j < 8; j++) { float ef = __expf((float)t[j] - mx); l += ef; e[j] = (_Float16)ef; }
        *(h8*)&rp[((c * 64 + lane) * 8) ^ xr] = e;
      }
#pragma unroll
      for (int o = 32; o; o >>= 1) l += __shfl_xor(l, o);
      float inv = 1.0f / l;
      if (lane == 0) invl[r] = inv;
      _Float16 hinv = (_Float16)inv;
#pragma unroll
      for (int c = 0; c < 4; ++c) {
        h8 e = *(const h8*)&rp[((c * 64 + lane) * 8) ^ xr];
        av[u][c] += e * hinv;           // v_pk_mul/add_f16
      }
    }
    __syncthreads();

    // ---- PV: wave = (d-tile, k-half); V (f16) read once per block-head.
    //      Two independent MFMA chains halve the serial dependency depth.
    {
      int dtl = w & 3, kh = w >> 2;
      const _Float16* vb = Vt + bh * DD * TT + (size_t)(dtl * 16 + m) * TT + kh * 1024 + kq * 8;
      const _Float16* ap = &sc[(size_t)m * 2048];
      int xr = (m & 7) << 3;
      f32x4 accA = {0.f, 0.f, 0.f, 0.f};
      f32x4 accB = {0.f, 0.f, 0.f, 0.f};
#pragma unroll 2
      for (int s = 0; s < 32; s += 2) {
        int ksw0 = (kh * 1024 + s * 32 + kq * 8) ^ xr;
        int ksw1 = (kh * 1024 + (s + 1) * 32 + kq * 8) ^ xr;
        h8 bv0 = *(const h8*)(vb + s * 32);
        h8 bv1 = *(const h8*)(vb + (s + 1) * 32);
        h8 a0 = *(const h8*)&ap[ksw0];
        h8 a1 = *(const h8*)&ap[ksw1];
        accA = MFMA_F16(a0, bv0, accA);
        accB = MFMA_F16(a1, bv1, accB);
      }
      if (kh == 1) {
#pragma unroll
        for (int e = 0; e < 4; e++)
          scr[dtl * 256 + (kq * 4 + e) * 16 + m] = accA[e] + accB[e];
      }
      __syncthreads();
      if (kh == 0) {
#pragma unroll
        for (int e = 0; e < 4; e++) {
          int ql = kq * 4 + e;
          float v0 = (accA[e] + accB[e] + scr[dtl * 256 + ql * 16 + m]) * invl[ql];
          attn[((size_t)(t0 + ql) * BB + b) * EE + h * DD + dtl * 16 + m] = f2bf(v0);
        }
      }
    }
    __syncthreads();   // sc/scr reads done before next head overwrites
  }

  // ---- write avg once: row t0 + w*2+u, cols (c*64+lane)*8 .. +7
#pragma unroll
  for (int u = 0; u < 2; ++u) {
    float* gp = avgp + ((size_t)b * TT + t0 + w * 2 + u) * TT;
#pragma unroll
    for (int c = 0; c < 4; ++c) {
      int cb = (c * 64 + lane) * 8;
      float4 o0 = {(float)av[u][c][0] * 0.0625f, (float)av[u][c][1] * 0.0625f,
                   (float)av[u][c][2] * 0.0625f, (float)av[u][c][3] * 0.0625f};
      float4 o1 = {(float)av[u][c][4] * 0.0625f, (float)av[u][c][5] * 0.0625f,
                   (float)av[u][c][6] * 0.0625f, (float)av[u][c][7] * 0.0625f};
      ((float4*)(gp + cb))[0] = o0;
      ((float4*)(gp + cb))[1] = o1;
    }
  }
}

// ---------------------------------------------------------------- output projection
__global__ __launch_bounds__(256) void gemm_out(
    const ushort* __restrict__ A, const ushort* __restrict__ W,
    const float* __restrict__ bias, float* __restrict__ out)
{
  __shared__ ushort As[128 * 32];
  __shared__ ushort Bs[128 * 32];
  const int K = EE;
  int tid = threadIdx.x;
  int bn = blockIdx.x, bm = blockIdx.y;
  int brow = bm * 128, bcol = bn * 128;
  int lane = tid & 63, wid = tid >> 6;
  int wm = wid >> 1, wn = wid & 1;
  int lr = lane & 15, kg = lane >> 4;

  f32x4 zero = {0.f, 0.f, 0.f, 0.f};
  f32x4 acc[4][4];
#pragma unroll
  for (int i = 0; i < 4; i++)
#pragma unroll
    for (int j = 0; j < 4; j++) acc[i][j] = zero;

  int r0 = tid >> 2, c0 = (tid & 3) * 8;
  const ushort* Abase = A + (size_t)brow * K;
  const ushort* Wbase = W + (size_t)bcol * K;

  for (int k0 = 0; k0 < K; k0 += 32) {
    __syncthreads();
    GL2L(Abase + (size_t)r0 * K + k0 + c0,        &As[tid * 8]);
    GL2L(Abase + (size_t)(r0 + 64) * K + k0 + c0, &As[(tid + 256) * 8]);
    GL2L(Wbase + (size_t)r0 * K + k0 + c0,        &Bs[tid * 8]);
    GL2L(Wbase + (size_t)(r0 + 64) * K + k0 + c0, &Bs[(tid + 256) * 8]);
    __syncthreads();
    s16x8 af[4], bfr[4];
#pragma unroll
    for (int i = 0; i < 4; i++) af[i]  = *(const s16x8*)&As[(wm * 64 + i * 16 + lr) * 32 + kg * 8];
#pragma unroll
    for (int j = 0; j < 4; j++) bfr[j] = *(const s16x8*)&Bs[(wn * 64 + j * 16 + lr) * 32 + kg * 8];
#pragma unroll
    for (int i = 0; i < 4; i++)
#pragma unroll
      for (int j = 0; j < 4; j++)
        acc[i][j] = MFMA_BF16(af[i], bfr[j], acc[i][j]);
  }

#pragma unroll
  for (int i = 0; i < 4; i++)
#pragma unroll
    for (int j = 0; j < 4; j++) {
      int n = bcol + wn * 64 + j * 16 + lr;
      float bv = bias[n];
#pragma unroll
      for (int e = 0; e < 4; e++) {
        int m = brow + wm * 64 + i * 16 + kg * 4 + e;
        out[(size_t)m * EE + n] = acc[i][j][e] + bv;
      }
    }
}

// ---------------------------------------------------------------- launch
extern "C" void kernel_launch(void* const* d_in, const int* in_sizes, int n_in,
                              void* d_out, int out_size, void* d_ws, size_t ws_size,
                              hipStream_t stream) {
  const float* x  = (const float*)d_in[0];
  const float* w1 = (const float*)d_in[1];
  const float* b1 = (const float*)d_in[2];
  const float* w2 = (const float*)d_in[3];
  const float* b2 = (const float*)d_in[4];
  float* out = (float*)d_out;
  float* avg = out + (size_t)MR * EE;

  char* p = (char*)d_ws;
  ushort* Xb   = (ushort*)p; p += (size_t)MR * EE * 2;
  ushort* W1b  = (ushort*)p; p += (size_t)3 * EE * EE * 2;
  ushort* W2b  = (ushort*)p; p += (size_t)EE * EE * 2;
  ushort* Qb   = (ushort*)p; p += (size_t)BB * HH * TT * DD * 2;
  ushort* Kb   = (ushort*)p; p += (size_t)BB * HH * TT * DD * 2;
  ushort* Vt   = (ushort*)p; p += (size_t)BB * HH * TT * DD * 2;
  ushort* attn = (ushort*)p; p += (size_t)MR * EE * 2;
  (void)ws_size;

  cast_f32_bf16<<<1024, 256, 0, stream>>>(x,  Xb,  MR * EE / 4);
  cast_f32_bf16<<<512,  256, 0, stream>>>(w1, W1b, 3 * EE * EE / 4);
  cast_f32_bf16<<<256,  256, 0, stream>>>(w2, W2b, EE * EE / 4);
  gemm_qkv<<<dim3(24, 64), 256, 0, stream>>>(Xb, W1b, b1, Qb, Kb, Vt);
  attn_fused<<<dim3(TT / 16, BB), 512, 0, stream>>>(Qb, Kb, (const _Float16*)Vt, attn, avg);
  gemm_out<<<dim3(8, 64), 256, 0, stream>>>(attn, W2b, b2, out);
}

// Round 8
// 610.872 us; speedup vs baseline: 1.2199x; 1.1219x over previous
//
#include <hip/hip_runtime.h>
#include <hip/hip_bf16.h>
#include <cstdint>
#include <cstddef>
#include <cstring>

typedef __attribute__((ext_vector_type(8))) short s16x8;
typedef __attribute__((ext_vector_type(4))) float f32x4;
typedef __attribute__((ext_vector_type(8))) _Float16 h8;
typedef __attribute__((ext_vector_type(4))) _Float16 h4;
typedef __attribute__((ext_vector_type(2))) _Float16 h2;

#define TT 2048
#define BB 4
#define EE 1024
#define HH 16
#define DD 64
#define MR 8192   // T*B rows

#define MFMA_BF16(a,b,c) __builtin_amdgcn_mfma_f32_16x16x32_bf16(a,b,c,0,0,0)
#define MFMA_F16(a,b,c)  __builtin_amdgcn_mfma_f32_16x16x32_f16(a,b,c,0,0,0)

__device__ __forceinline__ ushort f2bf(float f) {
  uint32_t u = __float_as_uint(f);
  u += 0x7fffu + ((u >> 16) & 1u);   // RNE
  return (ushort)(u >> 16);
}

__device__ __forceinline__ uint32_t pk2u(h2 v) { uint32_t u; __builtin_memcpy(&u, &v, 4); return u; }
__device__ __forceinline__ h2 u2pk(uint32_t u) { h2 v; __builtin_memcpy(&v, &u, 4); return v; }

// global -> LDS async copy, 16B per lane. LDS dest must be wave-uniform base + lane*16.
#define GL2L(g, l) __builtin_amdgcn_global_load_lds( \
    (__attribute__((address_space(1))) void*)(g), \
    (__attribute__((address_space(3))) void*)(l), 16, 0, 0)

// ---------------------------------------------------------------- cast fp32->bf16
__global__ void cast_f32_bf16(const float* __restrict__ in, ushort* __restrict__ out, int n4) {
  int stride = gridDim.x * blockDim.x;
  for (int i = blockIdx.x * blockDim.x + threadIdx.x; i < n4; i += stride) {
    float4 v = ((const float4*)in)[i];
    ushort4 o;
    o.x = f2bf(v.x); o.y = f2bf(v.y); o.z = f2bf(v.z); o.w = f2bf(v.w);
    ((ushort4*)out)[i] = o;
  }
}

// ---------------------------------------------------------------- QKV projection
// C[m][n] = sum_k A[m][k]*W[n][k] + bias[n];  m=(t*4+b), n = sec*1024 + h*64 + d
// Q scaled by 0.125 -> bf16 [b][h][t][d]; K -> bf16 same; V -> f16 transposed [b][h][d][t].
__global__ __launch_bounds__(256) void gemm_qkv(
    const ushort* __restrict__ A, const ushort* __restrict__ W,
    const float* __restrict__ bias,
    ushort* __restrict__ Qb, ushort* __restrict__ Kb, ushort* __restrict__ Vt)
{
  __shared__ ushort As[128 * 32];
  __shared__ ushort Bs[128 * 32];
  const int K = EE;
  int tid = threadIdx.x;
  int bn = blockIdx.x, bm = blockIdx.y;
  int brow = bm * 128, bcol = bn * 128;
  int lane = tid & 63, wid = tid >> 6;
  int wm = wid >> 1, wn = wid & 1;
  int lr = lane & 15, kg = lane >> 4;

  f32x4 zero = {0.f, 0.f, 0.f, 0.f};
  f32x4 acc[4][4];
#pragma unroll
  for (int i = 0; i < 4; i++)
#pragma unroll
    for (int j = 0; j < 4; j++) acc[i][j] = zero;

  int r0 = tid >> 2, c0 = (tid & 3) * 8;
  const ushort* Abase = A + (size_t)brow * K;
  const ushort* Wbase = W + (size_t)bcol * K;

  for (int k0 = 0; k0 < K; k0 += 32) {
    __syncthreads();
    GL2L(Abase + (size_t)r0 * K + k0 + c0,        &As[tid * 8]);
    GL2L(Abase + (size_t)(r0 + 64) * K + k0 + c0, &As[(tid + 256) * 8]);
    GL2L(Wbase + (size_t)r0 * K + k0 + c0,        &Bs[tid * 8]);
    GL2L(Wbase + (size_t)(r0 + 64) * K + k0 + c0, &Bs[(tid + 256) * 8]);
    __syncthreads();
    s16x8 af[4], bfr[4];
#pragma unroll
    for (int i = 0; i < 4; i++) af[i]  = *(const s16x8*)&As[(wm * 64 + i * 16 + lr) * 32 + kg * 8];
#pragma unroll
    for (int j = 0; j < 4; j++) bfr[j] = *(const s16x8*)&Bs[(wn * 64 + j * 16 + lr) * 32 + kg * 8];
#pragma unroll
    for (int i = 0; i < 4; i++)
#pragma unroll
      for (int j = 0; j < 4; j++)
        acc[i][j] = MFMA_BF16(af[i], bfr[j], acc[i][j]);
  }

#pragma unroll
  for (int i = 0; i < 4; i++)
#pragma unroll
    for (int j = 0; j < 4; j++) {
      int n = bcol + wn * 64 + j * 16 + lr;
      float bv = bias[n];
      int sec = n >> 10;
      int hd = n & 1023;
      int h = hd >> 6, d = hd & 63;
#pragma unroll
      for (int e = 0; e < 4; e++) {
        int m = brow + wm * 64 + i * 16 + kg * 4 + e;
        int t = m >> 2, b = m & 3;
        float v = acc[i][j][e] + bv;
        size_t hoff = (size_t)(b * HH + h);
        if (sec == 0)      Qb[(hoff * TT + t) * DD + d] = f2bf(v * 0.125f);
        else if (sec == 1) Kb[(hoff * TT + t) * DD + d] = f2bf(v);
        else { _Float16 hv = (_Float16)v; Vt[(hoff * DD + d) * TT + t] = *(ushort*)&hv; }
      }
    }
}

// ---------------------------------------------------------------- fused attention
// block = (qt, b): 16 q-rows x all 2048 keys x all 16 heads. 512 thr.
// Register-budget design (observed allocator behavior on this toolchain at a
// 128-total budget: fixed 64-arch / 64-acc split): the persistent per-thread
// avg accumulator (32 regs, packed f16) is placed in AGPRs explicitly via
// v_accvgpr_read/write inline asm with "a" class constraints, leaving the
// 64 arch VGPRs for phase transients (~50 live). MFMA accs take ~12 AGPRs;
// total AGPR ~44 <= 64. waves_per_eu(4) => 2 blocks/CU with the 70KB LDS.
__attribute__((amdgpu_waves_per_eu(4)))
__global__ __launch_bounds__(512) void attn_fused(
    const ushort* __restrict__ Qb, const ushort* __restrict__ Kb,
    const _Float16* __restrict__ Vt, ushort* __restrict__ attn,
    float* __restrict__ avgp)
{
  __shared__ _Float16 sc[16 * 2048];   // 64 KB, column-swizzled: col ^ ((row&7)<<3)
  __shared__ float scr[1024];          // 4 KB PV partial-reduction scratch
  __shared__ float invl[16];

  const int qt = blockIdx.x;      // 0..127
  const int b  = blockIdx.y;      // 0..3
  const int tid = threadIdx.x;
  const int lane = tid & 63;
  const int w = tid >> 6;         // wave 0..7
  const int m = lane & 15;
  const int kq = lane >> 4;       // frag k-chunk == C-layout row group
  const int t0 = qt * 16;

  // per-thread avg accumulator in AGPRs: rows w*2+u, cols (c*64+lane)*8+j.
  // Each u32 holds 2 packed f16. Only touched via accvgpr read/write asm.
  uint32_t avr[2][4][4];
  {
    uint32_t zu = 0;
#pragma unroll
    for (int u = 0; u < 2; u++)
#pragma unroll
      for (int c = 0; c < 4; c++)
#pragma unroll
        for (int j = 0; j < 4; j++)
          asm("v_accvgpr_write_b32 %0, %1" : "=a"(avr[u][c][j]) : "v"(zu));
  }

  for (int h = 0; h < HH; ++h) {
    const size_t bh = (size_t)b * HH + h;

    // ---- Q fragments (bf16), Q pre-scaled by 1/8
    const ushort* qp = Qb + (bh * TT + t0) * DD;
    s16x8 q0 = *(const s16x8*)&qp[(size_t)m * DD + kq * 8];
    s16x8 q1 = *(const s16x8*)&qp[(size_t)m * DD + 32 + kq * 8];

    // ---- QK^T: wave w owns k-tiles w*16 .. w*16+15 (keys w*256..+255)
    const ushort* kbase = Kb + bh * TT * DD;
#pragma unroll 2
    for (int i = 0; i < 16; ++i) {
      int nt = w * 16 + i;
      const ushort* kr = kbase + (size_t)(nt * 16 + m) * DD + kq * 8;
      s16x8 a0 = *(const s16x8*)kr;
      s16x8 a1 = *(const s16x8*)(kr + 32);
      f32x4 c0 = {0.f, 0.f, 0.f, 0.f};
      c0 = MFMA_BF16(a0, q0, c0);
      c0 = MFMA_BF16(a1, q1, c0);
      // lane holds S[k = nt*16 + kq*4 + e][q = m] -> 4 k-consecutive f16, packed write
      int ksw = (nt * 16 + kq * 4) ^ ((m & 7) << 3);
      h4 p0;
#pragma unroll
      for (int e = 0; e < 4; e++) p0[e] = (_Float16)c0[e];
      *(h4*)&sc[(size_t)m * 2048 + ksw] = p0;
    }
    __syncthreads();

    // ---- softmax: wave w owns rows w*2, w*2+1. 3 sweeps over the LDS row so
    //      at most one h8 chunk is live; avg folded into AGPR accumulator.
#pragma unroll
    for (int u = 0; u < 2; ++u) {
      int r = w * 2 + u;
      _Float16* rp = &sc[(size_t)r * 2048];
      int xr = (r & 7) << 3;
      float mx = -3e38f;
#pragma unroll
      for (int c = 0; c < 4; ++c) {
        h8 t = *(const h8*)&rp[((c * 64 + lane) * 8) ^ xr];
#pragma unroll
        for (int j = 0; j < 8; j++) mx = fmaxf(mx, (float)t[j]);
      }
#pragma unroll
      for (int o = 32; o; o >>= 1) mx = fmaxf(mx, __shfl_xor(mx, o));
      float l = 0.f;
#pragma unroll
      for (int c = 0; c < 4; ++c) {
        h8 t = *(const h8*)&rp[((c * 64 + lane) * 8) ^ xr];
        h8 e;
#pragma unroll
        for (int j = 0; j < 8; j++) { float ef = __expf((float)t[j] - mx); l += ef; e[j] = (_Float16)ef; }
        *(h8*)&rp[((c * 64 + lane) * 8) ^ xr] = e;
      }
#pragma unroll
      for (int o = 32; o; o >>= 1) l += __shfl_xor(l, o);
      float inv = 1.0f / l;
      if (lane == 0) invl[r] = inv;
      _Float16 hinv = (_Float16)inv;
      h2 hinv2 = {hinv, hinv};
#pragma unroll
      for (int c = 0; c < 4; ++c) {
        h8 e = *(const h8*)&rp[((c * 64 + lane) * 8) ^ xr];
#pragma unroll
        for (int j = 0; j < 4; ++j) {
          uint32_t x;
          asm("v_accvgpr_read_b32 %0, %1" : "=v"(x) : "a"(avr[u][c][j]));
          h2 xv = u2pk(x);
          h2 ep = {e[2 * j], e[2 * j + 1]};
          xv += ep * hinv2;             // v_pk_fma_f16 in VGPRs
          asm("v_accvgpr_write_b32 %0, %1" : "=a"(avr[u][c][j]) : "v"(pk2u(xv)));
        }
      }
    }
    __syncthreads();

    // ---- PV: wave = (d-tile, k-half); V (f16) read once per block-head.
    //      Two independent MFMA chains halve the serial dependency depth.
    {
      int dtl = w & 3, kh = w >> 2;
      const _Float16* vb = Vt + bh * DD * TT + (size_t)(dtl * 16 + m) * TT + kh * 1024 + kq * 8;
      const _Float16* ap = &sc[(size_t)m * 2048];
      int xr = (m & 7) << 3;
      f32x4 accA = {0.f, 0.f, 0.f, 0.f};
      f32x4 accB = {0.f, 0.f, 0.f, 0.f};
#pragma unroll 2
      for (int s = 0; s < 32; s += 2) {
        int ksw0 = (kh * 1024 + s * 32 + kq * 8) ^ xr;
        int ksw1 = (kh * 1024 + (s + 1) * 32 + kq * 8) ^ xr;
        h8 bv0 = *(const h8*)(vb + s * 32);
        h8 bv1 = *(const h8*)(vb + (s + 1) * 32);
        h8 a0 = *(const h8*)&ap[ksw0];
        h8 a1 = *(const h8*)&ap[ksw1];
        accA = MFMA_F16(a0, bv0, accA);
        accB = MFMA_F16(a1, bv1, accB);
      }
      if (kh == 1) {
#pragma unroll
        for (int e = 0; e < 4; e++)
          scr[dtl * 256 + (kq * 4 + e) * 16 + m] = accA[e] + accB[e];
      }
      __syncthreads();
      if (kh == 0) {
#pragma unroll
        for (int e = 0; e < 4; e++) {
          int ql = kq * 4 + e;
          float v0 = (accA[e] + accB[e] + scr[dtl * 256 + ql * 16 + m]) * invl[ql];
          attn[((size_t)(t0 + ql) * BB + b) * EE + h * DD + dtl * 16 + m] = f2bf(v0);
        }
      }
    }
    __syncthreads();   // sc/scr reads done before next head overwrites
  }

  // ---- write avg once: row t0 + w*2+u, cols (c*64+lane)*8 .. +7
#pragma unroll
  for (int u = 0; u < 2; ++u) {
    float* gp = avgp + ((size_t)b * TT + t0 + w * 2 + u) * TT;
#pragma unroll
    for (int c = 0; c < 4; ++c) {
      int cb = (c * 64 + lane) * 8;
      float o[8];
#pragma unroll
      for (int j = 0; j < 4; ++j) {
        uint32_t x;
        asm("v_accvgpr_read_b32 %0, %1" : "=v"(x) : "a"(avr[u][c][j]));
        h2 xv = u2pk(x);
        o[2 * j]     = (float)xv[0] * 0.0625f;
        o[2 * j + 1] = (float)xv[1] * 0.0625f;
      }
      float4 o0 = {o[0], o[1], o[2], o[3]};
      float4 o1 = {o[4], o[5], o[6], o[7]};
      ((float4*)(gp + cb))[0] = o0;
      ((float4*)(gp + cb))[1] = o1;
    }
  }
}

// ---------------------------------------------------------------- output projection
__global__ __launch_bounds__(256) void gemm_out(
    const ushort* __restrict__ A, const ushort* __restrict__ W,
    const float* __restrict__ bias, float* __restrict__ out)
{
  __shared__ ushort As[128 * 32];
  __shared__ ushort Bs[128 * 32];
  const int K = EE;
  int tid = threadIdx.x;
  int bn = blockIdx.x, bm = blockIdx.y;
  int brow = bm * 128, bcol = bn * 128;
  int lane = tid & 63, wid = tid >> 6;
  int wm = wid >> 1, wn = wid & 1;
  int lr = lane & 15, kg = lane >> 4;

  f32x4 zero = {0.f, 0.f, 0.f, 0.f};
  f32x4 acc[4][4];
#pragma unroll
  for (int i = 0; i < 4; i++)
#pragma unroll
    for (int j = 0; j < 4; j++) acc[i][j] = zero;

  int r0 = tid >> 2, c0 = (tid & 3) * 8;
  const ushort* Abase = A + (size_t)brow * K;
  const ushort* Wbase = W + (size_t)bcol * K;

  for (int k0 = 0; k0 < K; k0 += 32) {
    __syncthreads();
    GL2L(Abase + (size_t)r0 * K + k0 + c0,        &As[tid * 8]);
    GL2L(Abase + (size_t)(r0 + 64) * K + k0 + c0, &As[(tid + 256) * 8]);
    GL2L(Wbase + (size_t)r0 * K + k0 + c0,        &Bs[tid * 8]);
    GL2L(Wbase + (size_t)(r0 + 64) * K + k0 + c0, &Bs[(tid + 256) * 8]);
    __syncthreads();
    s16x8 af[4], bfr[4];
#pragma unroll
    for (int i = 0; i < 4; i++) af[i]  = *(const s16x8*)&As[(wm * 64 + i * 16 + lr) * 32 + kg * 8];
#pragma unroll
    for (int j = 0; j < 4; j++) bfr[j] = *(const s16x8*)&Bs[(wn * 64 + j * 16 + lr) * 32 + kg * 8];
#pragma unroll
    for (int i = 0; i < 4; i++)
#pragma unroll
      for (int j = 0; j < 4; j++)
        acc[i][j] = MFMA_BF16(af[i], bfr[j], acc[i][j]);
  }

#pragma unroll
  for (int i = 0; i < 4; i++)
#pragma unroll
    for (int j = 0; j < 4; j++) {
      int n = bcol + wn * 64 + j * 16 + lr;
      float bv = bias[n];
#pragma unroll
      for (int e = 0; e < 4; e++) {
        int m = brow + wm * 64 + i * 16 + kg * 4 + e;
        out[(size_t)m * EE + n] = acc[i][j][e] + bv;
      }
    }
}

// ---------------------------------------------------------------- launch
extern "C" void kernel_launch(void* const* d_in, const int* in_sizes, int n_in,
                              void* d_out, int out_size, void* d_ws, size_t ws_size,
                              hipStream_t stream) {
  const float* x  = (const float*)d_in[0];
  const float* w1 = (const float*)d_in[1];
  const float* b1 = (const float*)d_in[2];
  const float* w2 = (const float*)d_in[3];
  const float* b2 = (const float*)d_in[4];
  float* out = (float*)d_out;
  float* avg = out + (size_t)MR * EE;

  char* p = (char*)d_ws;
  ushort* Xb   = (ushort*)p; p += (size_t)MR * EE * 2;
  ushort* W1b  = (ushort*)p; p += (size_t)3 * EE * EE * 2;
  ushort* W2b  = (ushort*)p; p += (size_t)EE * EE * 2;
  ushort* Qb   = (ushort*)p; p += (size_t)BB * HH * TT * DD * 2;
  ushort* Kb   = (ushort*)p; p += (size_t)BB * HH * TT * DD * 2;
  ushort* Vt   = (ushort*)p; p += (size_t)BB * HH * TT * DD * 2;
  ushort* attn = (ushort*)p; p += (size_t)MR * EE * 2;
  (void)ws_size;

  cast_f32_bf16<<<1024, 256, 0, stream>>>(x,  Xb,  MR * EE / 4);
  cast_f32_bf16<<<512,  256, 0, stream>>>(w1, W1b, 3 * EE * EE / 4);
  cast_f32_bf16<<<256,  256, 0, stream>>>(w2, W2b, EE * EE / 4);
  gemm_qkv<<<dim3(24, 64), 256, 0, stream>>>(Xb, W1b, b1, Qb, Kb, Vt);
  attn_fused<<<dim3(TT / 16, BB), 512, 0, stream>>>(Qb, Kb, (const _Float16*)Vt, attn, avg);
  gemm_out<<<dim3(8, 64), 256, 0, stream>>>(attn, W2b, b2, out);
}

// Round 9
// 466.083 us; speedup vs baseline: 1.5989x; 1.3107x over previous
//
#include <hip/hip_runtime.h>
#include <hip/hip_bf16.h>
#include <cstdint>
#include <cstddef>

typedef __attribute__((ext_vector_type(8))) short s16x8;
typedef __attribute__((ext_vector_type(4))) float f32x4;
typedef __attribute__((ext_vector_type(8))) _Float16 h8;
typedef __attribute__((ext_vector_type(4))) _Float16 h4;

#define TT 2048
#define BB 4
#define EE 1024
#define HH 16
#define DD 64
#define MR 8192   // T*B rows

#define MFMA_BF16(a,b,c) __builtin_amdgcn_mfma_f32_16x16x32_bf16(a,b,c,0,0,0)
#define MFMA_F16(a,b,c)  __builtin_amdgcn_mfma_f32_16x16x32_f16(a,b,c,0,0,0)

__device__ __forceinline__ ushort f2bf(float f) {
  uint32_t u = __float_as_uint(f);
  u += 0x7fffu + ((u >> 16) & 1u);   // RNE
  return (ushort)(u >> 16);
}

// global -> LDS async copy, 16B per lane. LDS dest must be wave-uniform base + lane*16.
#define GL2L(g, l) __builtin_amdgcn_global_load_lds( \
    (__attribute__((address_space(1))) void*)(g), \
    (__attribute__((address_space(3))) void*)(l), 16, 0, 0)

// ---------------------------------------------------------------- cast fp32->bf16
__global__ void cast_f32_bf16(const float* __restrict__ in, ushort* __restrict__ out, int n4) {
  int stride = gridDim.x * blockDim.x;
  for (int i = blockIdx.x * blockDim.x + threadIdx.x; i < n4; i += stride) {
    float4 v = ((const float4*)in)[i];
    ushort4 o;
    o.x = f2bf(v.x); o.y = f2bf(v.y); o.z = f2bf(v.z); o.w = f2bf(v.w);
    ((ushort4*)out)[i] = o;
  }
}

// ---------------------------------------------------------------- QKV projection
// C[m][n] = sum_k A[m][k]*W[n][k] + bias[n];  m=(t*4+b), n = sec*1024 + h*64 + d
// Q scaled by 0.125 -> bf16 [b][h][t][d]; K -> bf16 same; V -> f16 transposed [b][h][d][t].
__global__ __launch_bounds__(256) void gemm_qkv(
    const ushort* __restrict__ A, const ushort* __restrict__ W,
    const float* __restrict__ bias,
    ushort* __restrict__ Qb, ushort* __restrict__ Kb, ushort* __restrict__ Vt)
{
  __shared__ ushort As[128 * 32];
  __shared__ ushort Bs[128 * 32];
  const int K = EE;
  int tid = threadIdx.x;
  int bn = blockIdx.x, bm = blockIdx.y;
  int brow = bm * 128, bcol = bn * 128;
  int lane = tid & 63, wid = tid >> 6;
  int wm = wid >> 1, wn = wid & 1;
  int lr = lane & 15, kg = lane >> 4;

  f32x4 zero = {0.f, 0.f, 0.f, 0.f};
  f32x4 acc[4][4];
#pragma unroll
  for (int i = 0; i < 4; i++)
#pragma unroll
    for (int j = 0; j < 4; j++) acc[i][j] = zero;

  int r0 = tid >> 2, c0 = (tid & 3) * 8;
  const ushort* Abase = A + (size_t)brow * K;
  const ushort* Wbase = W + (size_t)bcol * K;

  for (int k0 = 0; k0 < K; k0 += 32) {
    __syncthreads();
    GL2L(Abase + (size_t)r0 * K + k0 + c0,        &As[tid * 8]);
    GL2L(Abase + (size_t)(r0 + 64) * K + k0 + c0, &As[(tid + 256) * 8]);
    GL2L(Wbase + (size_t)r0 * K + k0 + c0,        &Bs[tid * 8]);
    GL2L(Wbase + (size_t)(r0 + 64) * K + k0 + c0, &Bs[(tid + 256) * 8]);
    __syncthreads();
    s16x8 af[4], bfr[4];
#pragma unroll
    for (int i = 0; i < 4; i++) af[i]  = *(const s16x8*)&As[(wm * 64 + i * 16 + lr) * 32 + kg * 8];
#pragma unroll
    for (int j = 0; j < 4; j++) bfr[j] = *(const s16x8*)&Bs[(wn * 64 + j * 16 + lr) * 32 + kg * 8];
#pragma unroll
    for (int i = 0; i < 4; i++)
#pragma unroll
      for (int j = 0; j < 4; j++)
        acc[i][j] = MFMA_BF16(af[i], bfr[j], acc[i][j]);
  }

#pragma unroll
  for (int i = 0; i < 4; i++)
#pragma unroll
    for (int j = 0; j < 4; j++) {
      int n = bcol + wn * 64 + j * 16 + lr;
      float bv = bias[n];
      int sec = n >> 10;
      int hd = n & 1023;
      int h = hd >> 6, d = hd & 63;
#pragma unroll
      for (int e = 0; e < 4; e++) {
        int m = brow + wm * 64 + i * 16 + kg * 4 + e;
        int t = m >> 2, b = m & 3;
        float v = acc[i][j][e] + bv;
        size_t hoff = (size_t)(b * HH + h);
        if (sec == 0)      Qb[(hoff * TT + t) * DD + d] = f2bf(v * 0.125f);
        else if (sec == 1) Kb[(hoff * TT + t) * DD + d] = f2bf(v);
        else { _Float16 hv = (_Float16)v; Vt[(hoff * DD + d) * TT + t] = *(ushort*)&hv; }
      }
    }
}

// ---------------------------------------------------------------- fused attention
// block = (qt, b): 32 q-rows x all 2048 keys x all 16 heads. 512 thr, 1 block/CU
// (LDS 140 KB), 2 waves/SIMD, fat register budget (no launch-bound cap) so the
// compiler can pipeline K/V loads 4-deep. Per head:
//   QK^T (swapped mfma, packed LDS writes, XOR swizzle) with FOLDED max-tracking
//   (f32 max on MFMA outputs + 2 shfl + pmax[32][8] reduce) -> no max sweep;
//   single exp sweep computing l and keeping the row's exp fragments in regs ->
//   av accumulated in packed-f16 regs after the l-ladder (no reload sweep);
//   PV f16 MFMA, 4 independent chains, (d-tile, k-half) waves + LDS reduction.
__global__ __launch_bounds__(512) void attn_fused(
    const ushort* __restrict__ Qb, const ushort* __restrict__ Kb,
    const _Float16* __restrict__ Vt, ushort* __restrict__ attn,
    float* __restrict__ avgp)
{
  __shared__ _Float16 sc[32 * 2048];   // 128 KB, column-swizzled: col ^ ((row&7)<<3)
  __shared__ float scr[2048];          // 8 KB PV partial-reduction scratch
  __shared__ float pmax[32][8];        // per-row per-wave partial maxima
  __shared__ float invl[32];

  const int qt = blockIdx.x;      // 0..63
  const int b  = blockIdx.y;      // 0..3
  const int tid = threadIdx.x;
  const int lane = tid & 63;
  const int w = tid >> 6;         // wave 0..7
  const int m = lane & 15;
  const int kq = lane >> 4;       // frag k-chunk == C-layout row group
  const int t0 = qt * 32;

  // per-thread avg accumulator, PACKED f16: rows w*4+u, cols (c*64+lane)*8+j
  h8 av[4][4];
#pragma unroll
  for (int u = 0; u < 4; u++)
#pragma unroll
    for (int c = 0; c < 4; c++)
#pragma unroll
      for (int j = 0; j < 8; j++) av[u][c][j] = (_Float16)0.f;

  for (int h = 0; h < HH; ++h) {
    const size_t bh = (size_t)b * HH + h;

    // ---- Q fragments (bf16), rows m and 16+m; Q pre-scaled by 1/8
    const ushort* qp = Qb + (bh * TT + t0) * DD;
    s16x8 q00 = *(const s16x8*)&qp[(size_t)m * DD + kq * 8];
    s16x8 q01 = *(const s16x8*)&qp[(size_t)m * DD + 32 + kq * 8];
    s16x8 q10 = *(const s16x8*)&qp[(size_t)(16 + m) * DD + kq * 8];
    s16x8 q11 = *(const s16x8*)&qp[(size_t)(16 + m) * DD + 32 + kq * 8];

    // ---- QK^T with folded running max: wave w owns keys w*256..+255
    const ushort* kbase = Kb + bh * TT * DD;
    float mx0 = -3e38f, mx1 = -3e38f;
#pragma unroll 4
    for (int i = 0; i < 16; ++i) {
      int nt = w * 16 + i;
      const ushort* kr = kbase + (size_t)(nt * 16 + m) * DD + kq * 8;
      s16x8 a0 = *(const s16x8*)kr;
      s16x8 a1 = *(const s16x8*)(kr + 32);
      f32x4 c0 = {0.f, 0.f, 0.f, 0.f}, c1 = {0.f, 0.f, 0.f, 0.f};
      c0 = MFMA_BF16(a0, q00, c0); c0 = MFMA_BF16(a1, q01, c0);
      c1 = MFMA_BF16(a0, q10, c1); c1 = MFMA_BF16(a1, q11, c1);
      // lane holds S[k = nt*16 + kq*4 + e][q = m (+16)] -> packed h4 writes
      int ksw = (nt * 16 + kq * 4) ^ ((m & 7) << 3);
      h4 p0, p1;
#pragma unroll
      for (int e = 0; e < 4; e++) {
        mx0 = fmaxf(mx0, c0[e]); mx1 = fmaxf(mx1, c1[e]);
        p0[e] = (_Float16)c0[e]; p1[e] = (_Float16)c1[e];
      }
      *(h4*)&sc[(size_t)m * 2048 + ksw] = p0;
      *(h4*)&sc[(size_t)(16 + m) * 2048 + ksw] = p1;
    }
    // reduce over the 4 kq lane-groups (lanes with equal m): xor 16, 32
    mx0 = fmaxf(mx0, __shfl_xor(mx0, 16)); mx0 = fmaxf(mx0, __shfl_xor(mx0, 32));
    mx1 = fmaxf(mx1, __shfl_xor(mx1, 16)); mx1 = fmaxf(mx1, __shfl_xor(mx1, 32));
    if (lane < 16) { pmax[m][w] = mx0; pmax[16 + m][w] = mx1; }
    __syncthreads();

    // ---- softmax: wave w owns rows w*4..w*4+3; ONE sweep (exp + l + av-frags)
#pragma unroll
    for (int u = 0; u < 4; ++u) {
      int r = w * 4 + u;
      _Float16* rp = &sc[(size_t)r * 2048];
      int xr = (r & 7) << 3;
      float mx = -3e38f;
#pragma unroll
      for (int j = 0; j < 8; ++j) mx = fmaxf(mx, pmax[r][j]);
      float l = 0.f;
      h8 eh[4];
#pragma unroll
      for (int c = 0; c < 4; ++c) {
        h8 t = *(const h8*)&rp[((c * 64 + lane) * 8) ^ xr];
        h8 e;
#pragma unroll
        for (int j = 0; j < 8; j++) { float ef = __expf((float)t[j] - mx); l += ef; e[j] = (_Float16)ef; }
        *(h8*)&rp[((c * 64 + lane) * 8) ^ xr] = e;
        eh[c] = e;
      }
#pragma unroll
      for (int o = 32; o; o >>= 1) l += __shfl_xor(l, o);
      float inv = 1.0f / l;
      if (lane == 0) invl[r] = inv;
      _Float16 hinv = (_Float16)inv;
#pragma unroll
      for (int c = 0; c < 4; ++c)
#pragma unroll
        for (int j = 0; j < 8; j++)
          av[u][c][j] += eh[c][j] * hinv;     // packs to v_pk_fma_f16
    }
    __syncthreads();

    // ---- PV: wave = (d-tile, k-half); rows m and 16+m; 4 independent chains
    {
      int dtl = w & 3, kh = w >> 2;
      const _Float16* vb = Vt + bh * DD * TT + (size_t)(dtl * 16 + m) * TT + kh * 1024 + kq * 8;
      const _Float16* a0p = &sc[(size_t)m * 2048];
      const _Float16* a1p = &sc[(size_t)(16 + m) * 2048];
      int xr = (m & 7) << 3;
      f32x4 accA0 = {0.f, 0.f, 0.f, 0.f}, accB0 = {0.f, 0.f, 0.f, 0.f};
      f32x4 accA1 = {0.f, 0.f, 0.f, 0.f}, accB1 = {0.f, 0.f, 0.f, 0.f};
#pragma unroll 2
      for (int s = 0; s < 32; s += 2) {
        int ksw0 = (kh * 1024 + s * 32 + kq * 8) ^ xr;
        int ksw1 = (kh * 1024 + (s + 1) * 32 + kq * 8) ^ xr;
        h8 bv0 = *(const h8*)(vb + s * 32);
        h8 bv1 = *(const h8*)(vb + (s + 1) * 32);
        h8 a00 = *(const h8*)&a0p[ksw0];
        h8 a01 = *(const h8*)&a0p[ksw1];
        h8 a10 = *(const h8*)&a1p[ksw0];
        h8 a11 = *(const h8*)&a1p[ksw1];
        accA0 = MFMA_F16(a00, bv0, accA0);
        accB0 = MFMA_F16(a01, bv1, accB0);
        accA1 = MFMA_F16(a10, bv0, accA1);
        accB1 = MFMA_F16(a11, bv1, accB1);
      }
      if (kh == 1) {
#pragma unroll
        for (int e = 0; e < 4; e++) {
          scr[(dtl * 2 + 0) * 256 + (kq * 4 + e) * 16 + m] = accA0[e] + accB0[e];
          scr[(dtl * 2 + 1) * 256 + (kq * 4 + e) * 16 + m] = accA1[e] + accB1[e];
        }
      }
      __syncthreads();
      if (kh == 0) {
#pragma unroll
        for (int e = 0; e < 4; e++) {
          int ql = kq * 4 + e;
          float v0 = (accA0[e] + accB0[e] + scr[(dtl * 2 + 0) * 256 + ql * 16 + m]) * invl[ql];
          float v1 = (accA1[e] + accB1[e] + scr[(dtl * 2 + 1) * 256 + ql * 16 + m]) * invl[16 + ql];
          attn[((size_t)(t0 + ql) * BB + b) * EE + h * DD + dtl * 16 + m] = f2bf(v0);
          attn[((size_t)(t0 + 16 + ql) * BB + b) * EE + h * DD + dtl * 16 + m] = f2bf(v1);
        }
      }
    }
    __syncthreads();   // sc/scr reads done before next head overwrites
  }

  // ---- write avg once: row t0 + w*4+u, cols (c*64+lane)*8 .. +7
#pragma unroll
  for (int u = 0; u < 4; ++u) {
    float* gp = avgp + ((size_t)b * TT + t0 + w * 4 + u) * TT;
#pragma unroll
    for (int c = 0; c < 4; ++c) {
      int cb = (c * 64 + lane) * 8;
      float4 o0 = {(float)av[u][c][0] * 0.0625f, (float)av[u][c][1] * 0.0625f,
                   (float)av[u][c][2] * 0.0625f, (float)av[u][c][3] * 0.0625f};
      float4 o1 = {(float)av[u][c][4] * 0.0625f, (float)av[u][c][5] * 0.0625f,
                   (float)av[u][c][6] * 0.0625f, (float)av[u][c][7] * 0.0625f};
      ((float4*)(gp + cb))[0] = o0;
      ((float4*)(gp + cb))[1] = o1;
    }
  }
}

// ---------------------------------------------------------------- output projection
__global__ __launch_bounds__(256) void gemm_out(
    const ushort* __restrict__ A, const ushort* __restrict__ W,
    const float* __restrict__ bias, float* __restrict__ out)
{
  __shared__ ushort As[128 * 32];
  __shared__ ushort Bs[128 * 32];
  const int K = EE;
  int tid = threadIdx.x;
  int bn = blockIdx.x, bm = blockIdx.y;
  int brow = bm * 128, bcol = bn * 128;
  int lane = tid & 63, wid = tid >> 6;
  int wm = wid >> 1, wn = wid & 1;
  int lr = lane & 15, kg = lane >> 4;

  f32x4 zero = {0.f, 0.f, 0.f, 0.f};
  f32x4 acc[4][4];
#pragma unroll
  for (int i = 0; i < 4; i++)
#pragma unroll
    for (int j = 0; j < 4; j++) acc[i][j] = zero;

  int r0 = tid >> 2, c0 = (tid & 3) * 8;
  const ushort* Abase = A + (size_t)brow * K;
  const ushort* Wbase = W + (size_t)bcol * K;

  for (int k0 = 0; k0 < K; k0 += 32) {
    __syncthreads();
    GL2L(Abase + (size_t)r0 * K + k0 + c0,        &As[tid * 8]);
    GL2L(Abase + (size_t)(r0 + 64) * K + k0 + c0, &As[(tid + 256) * 8]);
    GL2L(Wbase + (size_t)r0 * K + k0 + c0,        &Bs[tid * 8]);
    GL2L(Wbase + (size_t)(r0 + 64) * K + k0 + c0, &Bs[(tid + 256) * 8]);
    __syncthreads();
    s16x8 af[4], bfr[4];
#pragma unroll
    for (int i = 0; i < 4; i++) af[i]  = *(const s16x8*)&As[(wm * 64 + i * 16 + lr) * 32 + kg * 8];
#pragma unroll
    for (int j = 0; j < 4; j++) bfr[j] = *(const s16x8*)&Bs[(wn * 64 + j * 16 + lr) * 32 + kg * 8];
#pragma unroll
    for (int i = 0; i < 4; i++)
#pragma unroll
      for (int j = 0; j < 4; j++)
        acc[i][j] = MFMA_BF16(af[i], bfr[j], acc[i][j]);
  }

#pragma unroll
  for (int i = 0; i < 4; i++)
#pragma unroll
    for (int j = 0; j < 4; j++) {
      int n = bcol + wn * 64 + j * 16 + lr;
      float bv = bias[n];
#pragma unroll
      for (int e = 0; e < 4; e++) {
        int m = brow + wm * 64 + i * 16 + kg * 4 + e;
        out[(size_t)m * EE + n] = acc[i][j][e] + bv;
      }
    }
}

// ---------------------------------------------------------------- launch
extern "C" void kernel_launch(void* const* d_in, const int* in_sizes, int n_in,
                              void* d_out, int out_size, void* d_ws, size_t ws_size,
                              hipStream_t stream) {
  const float* x  = (const float*)d_in[0];
  const float* w1 = (const float*)d_in[1];
  const float* b1 = (const float*)d_in[2];
  const float* w2 = (const float*)d_in[3];
  const float* b2 = (const float*)d_in[4];
  float* out = (float*)d_out;
  float* avg = out + (size_t)MR * EE;

  char* p = (char*)d_ws;
  ushort* Xb   = (ushort*)p; p += (size_t)MR * EE * 2;
  ushort* W1b  = (ushort*)p; p += (size_t)3 * EE * EE * 2;
  ushort* W2b  = (ushort*)p; p += (size_t)EE * EE * 2;
  ushort* Qb   = (ushort*)p; p += (size_t)BB * HH * TT * DD * 2;
  ushort* Kb   = (ushort*)p; p += (size_t)BB * HH * TT * DD * 2;
  ushort* Vt   = (ushort*)p; p += (size_t)BB * HH * TT * DD * 2;
  ushort* attn = (ushort*)p; p += (size_t)MR * EE * 2;
  (void)ws_size;

  cast_f32_bf16<<<1024, 256, 0, stream>>>(x,  Xb,  MR * EE / 4);
  cast_f32_bf16<<<512,  256, 0, stream>>>(w1, W1b, 3 * EE * EE / 4);
  cast_f32_bf16<<<256,  256, 0, stream>>>(w2, W2b, EE * EE / 4);
  gemm_qkv<<<dim3(24, 64), 256, 0, stream>>>(Xb, W1b, b1, Qb, Kb, Vt);
  attn_fused<<<dim3(TT / 32, BB), 512, 0, stream>>>(Qb, Kb, (const _Float16*)Vt, attn, avg);
  gemm_out<<<dim3(8, 64), 256, 0, stream>>>(attn, W2b, b2, out);
}